// Round 1
// baseline (2633.683 us; speedup 1.0000x reference)
//
#include <hip/hip_runtime.h>

typedef unsigned short u16;
typedef unsigned int u32;
typedef __bf16 bf16x8 __attribute__((ext_vector_type(8)));
typedef float f32x4 __attribute__((ext_vector_type(4)));

#define N_NODES 32768
#define E_EDGES 262144
#define DP 320          // padded feature dim (300 -> 320)
#define KCAT 960        // padded concat K (900 -> 960)
#define LDSROW 40       // LDS row stride in bf16 elems (80B -> only 2-way bank aliasing)

__device__ __forceinline__ float b2f(u16 u) {
    union { u32 u; float f; } x; x.u = ((u32)u) << 16; return x.f;
}
__device__ __forceinline__ u16 f2b(float f) {
    union { float f; u32 u; } x; x.f = f;
    u32 r = x.u + 0x7FFF + ((x.u >> 16) & 1);
    return (u16)(r >> 16);
}

// ---------------- weight transpose+pad+convert:  dst[n][k] = W[k][n] ----------------
__global__ void convT_k(const float* __restrict__ src, int R, int C,
                        u16* __restrict__ dst, int KP, long total) {
    long id = (long)blockIdx.x * blockDim.x + threadIdx.x;
    if (id >= total) return;
    int n = (int)(id / KP), k = (int)(id % KP);
    dst[id] = (k < R && n < C) ? f2b(src[(long)k * C + n]) : (u16)0;
}

// ---------------- activation pad+convert: f32 MxC -> bf16 MxCP (pad 0) ----------------
__global__ void padconv_k(const float* __restrict__ src, int C,
                          u16* __restrict__ dst, int CP, long total) {
    long id = (long)blockIdx.x * blockDim.x + threadIdx.x;
    if (id >= total) return;
    int cw = CP >> 3;
    long row = id / cw;
    int c8 = (int)(id % cw) * 8;
    u32 w[4];
    #pragma unroll
    for (int p = 0; p < 4; ++p) {
        int c0 = c8 + 2 * p, c1 = c0 + 1;
        u16 lo = (c0 < C) ? f2b(src[row * C + c0]) : (u16)0;
        u16 hi = (c1 < C) ? f2b(src[row * C + c1]) : (u16)0;
        w[p] = (u32)lo | ((u32)hi << 16);
    }
    u32* d = (u32*)(dst + row * CP + c8);
    d[0] = w[0]; d[1] = w[1]; d[2] = w[2]; d[3] = w[3];
}

// ---------------- GEMM: C(Mx320) = A(MxKP bf16) * BT^T, BT is (320 x KP) n-major ----------------
// tile 64(M) x 320(N) x 32(K); 4 waves, wave w covers cols [80w, 80w+80)
__global__ __launch_bounds__(256) void gemm_k(
    const u16* __restrict__ A, int KP,
    const u16* __restrict__ BT,
    const float* __restrict__ bias,      // len 300 or null
    const float* __restrict__ add2,      // M x 300 f32 or null
    float* __restrict__ outF, int ostride, int ocols,   // or null
    u16* __restrict__ outB,              // M x 320 bf16 or null
    int relu)
{
    __shared__ u16 As[64 * LDSROW];
    __shared__ u16 Bs[320 * LDSROW];
    const int tid = threadIdx.x;
    const int w = tid >> 6, lane = tid & 63;
    const int tl = lane & 15, thi = lane >> 4;
    const long m0 = (long)blockIdx.x * 64;

    f32x4 acc[4][5];
    #pragma unroll
    for (int i = 0; i < 4; ++i)
        #pragma unroll
        for (int j = 0; j < 5; ++j) acc[i][j] = (f32x4)(0.f);

    const int ar = tid >> 2;            // staging row  (0..63)
    const int ack = (tid & 3) * 8;      // staging col offset (bf16 elems)
    const u16* Arow = A + (m0 + ar) * (long)KP + ack;

    const int nsteps = KP >> 5;
    for (int kt = 0; kt < nsteps; ++kt) {
        const int k0 = kt * 32;
        __syncthreads();
        // stage A tile (64x32)
        {
            const uint4 va = *(const uint4*)(Arow + k0);
            *(uint4*)(&As[ar * LDSROW + ack]) = va;
        }
        // stage B tile (320x32), 5 passes
        #pragma unroll
        for (int p = 0; p < 5; ++p) {
            int n = p * 64 + ar;
            const uint4 vb = *(const uint4*)(BT + (long)n * KP + k0 + ack);
            *(uint4*)(&Bs[n * LDSROW + ack]) = vb;
        }
        __syncthreads();

        bf16x8 a[4], b[5];
        #pragma unroll
        for (int fr = 0; fr < 4; ++fr)
            a[fr] = *(const bf16x8*)(&As[(fr * 16 + tl) * LDSROW + thi * 8]);
        #pragma unroll
        for (int fc = 0; fc < 5; ++fc)
            b[fc] = *(const bf16x8*)(&Bs[(w * 80 + fc * 16 + tl) * LDSROW + thi * 8]);
        #pragma unroll
        for (int fr = 0; fr < 4; ++fr)
            #pragma unroll
            for (int fc = 0; fc < 5; ++fc)
                acc[fr][fc] = __builtin_amdgcn_mfma_f32_16x16x32_bf16(a[fr], b[fc], acc[fr][fc], 0, 0, 0);
    }

    // epilogue
    #pragma unroll
    for (int fr = 0; fr < 4; ++fr) {
        #pragma unroll
        for (int fc = 0; fc < 5; ++fc) {
            const int gc = w * 80 + fc * 16 + tl;
            const float bs = (bias && gc < 300) ? bias[gc] : 0.f;
            #pragma unroll
            for (int r = 0; r < 4; ++r) {
                const long gr = m0 + fr * 16 + thi * 4 + r;
                float v = acc[fr][fc][r] + bs;
                if (add2 && gc < 300) v += add2[gr * 300 + gc];
                if (relu) v = fmaxf(v, 0.f);
                if (outF && gc < ocols) outF[gr * ostride + gc] = v;
                if (outB) outB[gr * 320 + gc] = f2b(v);
            }
        }
    }
}

// ---------------- fused 8-key 4-head attention, one wave per node ----------------
__global__ __launch_bounds__(256) void attn_k(
    const float* __restrict__ Q, const float* __restrict__ FV,
    const u16* __restrict__ HK, const u16* __restrict__ HV,
    const int* __restrict__ mail, u16* __restrict__ Ob)
{
    const int tid = threadIdx.x;
    const long n = (long)blockIdx.x * 4 + (tid >> 6);
    const int lane = tid & 63, g = lane >> 4, t = lane & 15;
    const float scale = 0.115470054f;  // 1/sqrt(75)
    const int dbase = g * 75 + t;

    float q[5];
    #pragma unroll
    for (int r = 0; r < 5; ++r) {
        q[r] = (t + 16 * r < 75) ? Q[n * 320 + dbase + 16 * r] * scale : 0.f;
    }

    int idx[8]; float s[8];
    #pragma unroll
    for (int j = 0; j < 8; ++j) {
        idx[j] = mail[n * 8 + j];
        const u16* kr = HK + (long)idx[j] * 320 + dbase;
        float p = 0.f;
        #pragma unroll
        for (int r = 0; r < 5; ++r) p += q[r] * b2f(kr[16 * r]);
        p += __shfl_xor(p, 8, 64);
        p += __shfl_xor(p, 4, 64);
        p += __shfl_xor(p, 2, 64);
        p += __shfl_xor(p, 1, 64);
        s[j] = p;
    }
    float mx = s[0];
    #pragma unroll
    for (int j = 1; j < 8; ++j) mx = fmaxf(mx, s[j]);
    float sum = 0.f;
    #pragma unroll
    for (int j = 0; j < 8; ++j) { s[j] = __expf(s[j] - mx); sum += s[j]; }
    const float inv = 1.f / sum;

    float o[5];
    #pragma unroll
    for (int r = 0; r < 5; ++r) o[r] = FV[n * 320 + dbase + 16 * r];  // softmax sums to 1
    #pragma unroll
    for (int j = 0; j < 8; ++j) {
        const float pj = s[j] * inv;
        const u16* vr = HV + (long)idx[j] * 320 + dbase;
        #pragma unroll
        for (int r = 0; r < 5; ++r) o[r] += pj * b2f(vr[16 * r]);
    }
    #pragma unroll
    for (int r = 0; r < 5; ++r)
        if (t + 16 * r < 75) Ob[n * 320 + dbase + 16 * r] = f2b(o[r]);
    if (lane < 20) Ob[n * 320 + 300 + lane] = 0;   // zero pad cols
}

// ---------------- mb = bf16( f_h[src[e]] - h[e^1] ) ----------------
__global__ void mb_k(const float* __restrict__ fh, const u16* __restrict__ hb,
                     const int* __restrict__ srcidx, u16* __restrict__ mb)
{
    long id = (long)blockIdx.x * blockDim.x + threadIdx.x;  // E*40 threads
    long e = id / 40;
    int c8 = (int)(id % 40) * 8;
    int sidx = srcidx[e];
    const float* fr = fh + (long)sidx * 320 + c8;
    const u16* hr = hb + (e ^ 1) * 320 + c8;
    u32 w[4];
    #pragma unroll
    for (int p = 0; p < 4; ++p) {
        u16 lo = f2b(fr[2 * p]     - b2f(hr[2 * p]));
        u16 hi = f2b(fr[2 * p + 1] - b2f(hr[2 * p + 1]));
        w[p] = (u32)lo | ((u32)hi << 16);
    }
    u32* d = (u32*)(mb + e * 320 + c8);
    d[0] = w[0]; d[1] = w[1]; d[2] = w[2]; d[3] = w[3];
}

// ---------------- build concat A = [mail_sum | f_h | f] (bf16, N x 960) ----------------
__global__ __launch_bounds__(256) void concat_k(
    const u16* __restrict__ hb, const float* __restrict__ fh,
    const float* __restrict__ f, const int* __restrict__ mail,
    u16* __restrict__ Acat)
{
    const long n = blockIdx.x;
    int m[8];
    #pragma unroll
    for (int j = 0; j < 8; ++j) m[j] = mail[n * 8 + j];
    for (int c = threadIdx.x; c < 960; c += 256) {
        float v;
        if (c < 300) {
            float s = 0.f;
            #pragma unroll
            for (int j = 0; j < 8; ++j) s += b2f(hb[(long)m[j] * 320 + c]);
            v = s;
        } else if (c < 600) v = fh[n * 320 + (c - 300)];
        else if (c < 900) v = f[n * 300 + (c - 600)];
        else v = 0.f;
        Acat[n * 960 + c] = f2b(v);
    }
}

extern "C" void kernel_launch(void* const* d_in, const int* in_sizes, int n_in,
                              void* d_out, int out_size, void* d_ws, size_t ws_size,
                              hipStream_t stream)
{
    const int N = N_NODES, E = E_EDGES;
    const float* f    = (const float*)d_in[0];
    const float* x    = (const float*)d_in[1];
    const int*   mail = (const int*)d_in[2];
    const int*   srcx = (const int*)d_in[3];
    const float* Wq = (const float*)d_in[4];   const float* bq = (const float*)d_in[5];
    const float* Wk = (const float*)d_in[6];   const float* bk = (const float*)d_in[7];
    const float* Wv = (const float*)d_in[8];   const float* bv = (const float*)d_in[9];
    const float* Wo = (const float*)d_in[10];  const float* bo = (const float*)d_in[11];
    const float* Wmp = (const float*)d_in[12]; const float* bmp = (const float*)d_in[13];
    const float* Wlast = (const float*)d_in[14]; const float* blast = (const float*)d_in[15];
    float* out = (float*)d_out;

    char* ws = (char*)d_ws;
    size_t off = 0;
    auto alloc = [&](size_t b) -> void* {
        void* p = ws + off; off += (b + 255) & ~(size_t)255; return p;
    };
    u16* hb   = (u16*)alloc((size_t)E * DP * 2);   // h (bf16, padded)
    u16* HKb  = (u16*)alloc((size_t)E * DP * 2);   // HK; reused as mb
    u16* HVb  = (u16*)alloc((size_t)E * DP * 2);   // HV; reused as Acat
    float* Qf = (float*)alloc((size_t)N * DP * 4);
    float* FV = (float*)alloc((size_t)N * DP * 4);
    float* fh = (float*)alloc((size_t)N * DP * 4);
    u16* fhb  = (u16*)alloc((size_t)N * DP * 2);
    u16* Ob   = (u16*)alloc((size_t)N * DP * 2);
    u16* WqB  = (u16*)alloc(320 * 320 * 2);
    u16* WkB  = (u16*)alloc(320 * 320 * 2);
    u16* WvB  = (u16*)alloc(320 * 320 * 2);
    u16* WoB  = (u16*)alloc(320 * 320 * 2);
    u16* Wm0B = (u16*)alloc(320 * 320 * 2);
    u16* Wm1B = (u16*)alloc(320 * 320 * 2);
    u16* WcatB = (u16*)alloc((size_t)KCAT * 320 * 2);

    // ---- weights: transpose + pad + bf16 ----
    {
        long tot = (long)320 * 320;
        int blks = (int)((tot + 255) / 256);
        convT_k<<<blks, 256, 0, stream>>>(Wq, 300, 300, WqB, 320, tot);
        convT_k<<<blks, 256, 0, stream>>>(Wk, 300, 300, WkB, 320, tot);
        convT_k<<<blks, 256, 0, stream>>>(Wv, 300, 300, WvB, 320, tot);
        convT_k<<<blks, 256, 0, stream>>>(Wo, 300, 300, WoB, 320, tot);
        convT_k<<<blks, 256, 0, stream>>>(Wmp,          300, 300, Wm0B, 320, tot);
        convT_k<<<blks, 256, 0, stream>>>(Wmp + 90000,  300, 300, Wm1B, 320, tot);
        long totc = (long)320 * KCAT;
        convT_k<<<(int)((totc + 255) / 256), 256, 0, stream>>>(Wlast, 900, 300, WcatB, KCAT, totc);
    }
    // ---- activations: h0 = bf16(x), fh0 = bf16(f) ----
    {
        long totE = (long)E * (DP / 8);
        padconv_k<<<(int)((totE + 255) / 256), 256, 0, stream>>>(x, 300, hb, DP, totE);
        long totN = (long)N * (DP / 8);
        padconv_k<<<(int)((totN + 255) / 256), 256, 0, stream>>>(f, 300, fhb, DP, totN);
    }

    for (int it = 0; it < 2; ++it) {
        const u16* WmB = it ? Wm1B : Wm0B;
        const float* bmpi = bmp + it * 300;
        // Q = f_h @ Wq + bq            (f32)
        gemm_k<<<N / 64, 256, 0, stream>>>(fhb, 320, WqB, bq, nullptr, Qf, 320, 320, nullptr, 0);
        // FV = f_h @ Wv + bv           (f32)
        gemm_k<<<N / 64, 256, 0, stream>>>(fhb, 320, WvB, bv, nullptr, FV, 320, 320, nullptr, 0);
        // HK = h @ Wk + bk             (bf16)
        gemm_k<<<E / 64, 256, 0, stream>>>(hb, 320, WkB, bk, nullptr, nullptr, 0, 0, HKb, 0);
        // HV = h @ Wv                  (bf16)
        gemm_k<<<E / 64, 256, 0, stream>>>(hb, 320, WvB, nullptr, nullptr, nullptr, 0, 0, HVb, 0);
        // attention -> Ob (bf16)
        attn_k<<<N / 4, 256, 0, stream>>>(Qf, FV, HKb, HVb, mail, Ob);
        // f_h = O @ Wo + bo            (f32 + bf16)
        gemm_k<<<N / 64, 256, 0, stream>>>(Ob, 320, WoB, bo, nullptr, fh, 320, 320, fhb, 0);
        // mb = bf16(f_h[src] - h[e^1])   (reuse HKb)
        mb_k<<<(int)(((long)E * 40) / 256), 256, 0, stream>>>(fh, hb, srcx, HKb);
        // h = relu(x + mb @ Wmp + bmp)  (bf16)
        gemm_k<<<E / 64, 256, 0, stream>>>(HKb, 320, WmB, bmpi, x, nullptr, 0, 0, hb, 1);
    }

    // Acat = [mail_sum | f_h | f]  (reuse HVb)
    concat_k<<<N, 256, 0, stream>>>(hb, fh, f, mail, HVb);
    // out = Acat @ Wlast + blast   (f32, stride 300)
    gemm_k<<<N / 64, 256, 0, stream>>>(HVb, KCAT, WcatB, blast, nullptr, out, 300, 300, nullptr, 0);
}

// Round 2
// 2342.709 us; speedup vs baseline: 1.1242x; 1.1242x over previous
//
#include <hip/hip_runtime.h>

typedef unsigned short u16;
typedef unsigned int u32;
typedef __bf16 bf16x8 __attribute__((ext_vector_type(8)));
typedef float f32x4 __attribute__((ext_vector_type(4)));

#define N_NODES 32768
#define E_EDGES 262144
#define DP 320          // padded feature dim (300 -> 320)
#define KCAT 960        // padded concat K (900 -> 960)

__device__ __forceinline__ float b2f(u16 u) {
    union { u32 u; float f; } x; x.u = ((u32)u) << 16; return x.f;
}
__device__ __forceinline__ u16 f2b(float f) {
    union { float f; u32 u; } x; x.f = f;
    u32 r = x.u + 0x7FFF + ((x.u >> 16) & 1);
    return (u16)(r >> 16);
}

#define GLOAD16(g, l) \
    __builtin_amdgcn_global_load_lds((const __attribute__((address_space(1))) u32*)(g), \
                                     (__attribute__((address_space(3))) u32*)(l), 16, 0, 0)

// ---------------- weight transpose+pad+convert:  dst[n][k] = W[k][n] ----------------
__global__ void convT_k(const float* __restrict__ src, int R, int C,
                        u16* __restrict__ dst, int KP, long total) {
    long id = (long)blockIdx.x * blockDim.x + threadIdx.x;
    if (id >= total) return;
    int n = (int)(id / KP), k = (int)(id % KP);
    dst[id] = (k < R && n < C) ? f2b(src[(long)k * C + n]) : (u16)0;
}

// ---------------- activation pad+convert: f32 MxC -> bf16 MxCP (pad 0), dual dest ----------------
__global__ void padconv_k(const float* __restrict__ src, int C,
                          u16* __restrict__ dst, u16* __restrict__ dst2,
                          int CP, long total) {
    long id = (long)blockIdx.x * blockDim.x + threadIdx.x;
    if (id >= total) return;
    int cw = CP >> 3;
    long row = id / cw;
    int c8 = (int)(id % cw) * 8;
    u32 w[4];
    #pragma unroll
    for (int p = 0; p < 4; ++p) {
        int c0 = c8 + 2 * p, c1 = c0 + 1;
        u16 lo = (c0 < C) ? f2b(src[row * C + c0]) : (u16)0;
        u16 hi = (c1 < C) ? f2b(src[row * C + c1]) : (u16)0;
        w[p] = (u32)lo | ((u32)hi << 16);
    }
    u32* d = (u32*)(dst + row * CP + c8);
    d[0] = w[0]; d[1] = w[1]; d[2] = w[2]; d[3] = w[3];
    if (dst2) {
        u32* d2 = (u32*)(dst2 + row * CP + c8);
        d2[0] = w[0]; d2[1] = w[1]; d2[2] = w[2]; d2[3] = w[3];
    }
}

// ---------------- GEMM: C(Mx320) = A(MxKP bf16) * BT^T, BT is (320 x KP) n-major ----------------
// tile 64(M) x 320(N) x 64(K); 4 waves, wave w covers cols [80w, 80w+80)
// LDS layout: [row][64] bf16 (128B rows), 16B-slot XOR-swizzled by (row&7).
// Staged via global_load_lds (linear dest) with inverse-swizzled global source.
__global__ __launch_bounds__(256) void gemm_k(
    const u16* __restrict__ A, int KP,
    const u16* __restrict__ BT,
    const float* __restrict__ bias,      // len >=300 or null
    const float* __restrict__ add2f,     // M x 300 f32 or null
    const u16*  __restrict__ add2b,      // M x 320 bf16 or null
    float* __restrict__ outF, int ostride, int ocols,   // or null
    u16* __restrict__ outB,              // M x 320 bf16 or null
    int relu)
{
    __shared__ u16 As[64 * 64];     // 8 KB
    __shared__ u16 Bs[320 * 64];    // 40 KB
    const int tid = threadIdx.x;
    const int w = tid >> 6, lane = tid & 63;
    const int tl = lane & 15, thi = lane >> 4;
    const int sx = tl & 7;                 // read-side swizzle key
    const long m0 = (long)blockIdx.x * 64;
    const int w_u = __builtin_amdgcn_readfirstlane(w);

    const int lr = lane >> 3;              // row within 8-row chunk
    const int lu = lane & 7;               // 16B slot within 128B row
    const int su = lu ^ lr;                // inverse-swizzled source col-unit (const per thread)

    // staging base pointers
    const u16* gA = A  + (m0 + w * 16 + lr) * (long)KP + su * 8;
    const u16* gB = BT + (w * 8 + lr) * (long)KP + su * 8;

    f32x4 acc[4][5];
    #pragma unroll
    for (int i = 0; i < 4; ++i)
        #pragma unroll
        for (int j = 0; j < 5; ++j) acc[i][j] = (f32x4)(0.f);

    const int nst = KP >> 6;
    for (int kt = 0; kt < nst; ++kt) {
        const int k0 = kt * 64;
        // ---- async stage: A 64x64 (8 chunks), B 320x64 (40 chunks), 1KB per wave-chunk
        GLOAD16(gA + k0,               &As[(w_u * 2 + 0) * 512]);
        GLOAD16(gA + 8 * (long)KP + k0, &As[(w_u * 2 + 1) * 512]);
        #pragma unroll
        for (int i = 0; i < 10; ++i)
            GLOAD16(gB + 32 * (long)i * KP + k0, &Bs[(w_u + 4 * i) * 512]);
        __syncthreads();   // drains vmcnt -> LDS ready

        #pragma unroll
        for (int ks = 0; ks < 2; ++ks) {
            bf16x8 a[4], b[5];
            #pragma unroll
            for (int fr = 0; fr < 4; ++fr)
                a[fr] = *(const bf16x8*)&As[(fr * 16 + tl) * 64 + ((ks * 4 + thi) ^ sx) * 8];
            #pragma unroll
            for (int fc = 0; fc < 5; ++fc)
                b[fc] = *(const bf16x8*)&Bs[(w * 80 + fc * 16 + tl) * 64 + ((ks * 4 + thi) ^ sx) * 8];
            #pragma unroll
            for (int fr = 0; fr < 4; ++fr)
                #pragma unroll
                for (int fc = 0; fc < 5; ++fc)
                    acc[fr][fc] = __builtin_amdgcn_mfma_f32_16x16x32_bf16(a[fr], b[fc], acc[fr][fc], 0, 0, 0);
        }
        __syncthreads();   // protect LDS before next stage
    }

    // epilogue
    #pragma unroll
    for (int fr = 0; fr < 4; ++fr) {
        #pragma unroll
        for (int fc = 0; fc < 5; ++fc) {
            const int gc = w * 80 + fc * 16 + tl;
            const float bs = (bias && gc < 300) ? bias[gc] : 0.f;
            #pragma unroll
            for (int r = 0; r < 4; ++r) {
                const long gr = m0 + fr * 16 + thi * 4 + r;
                float v = acc[fr][fc][r] + bs;
                if (add2f && gc < 300) v += add2f[gr * 300 + gc];
                if (add2b) v += b2f(add2b[gr * 320 + gc]);
                if (relu) v = fmaxf(v, 0.f);
                if (outF && gc < ocols) outF[gr * ostride + gc] = v;
                if (outB) outB[gr * 320 + gc] = f2b(v);
            }
        }
    }
}

// ---------------- fused 8-key 4-head attention, one wave per node ----------------
__global__ __launch_bounds__(256) void attn_k(
    const float* __restrict__ Q, const float* __restrict__ FV,
    const u16* __restrict__ HK, const u16* __restrict__ HV,
    const int* __restrict__ mail, u16* __restrict__ Ob)
{
    const int tid = threadIdx.x;
    const long n = (long)blockIdx.x * 4 + (tid >> 6);
    const int lane = tid & 63, g = lane >> 4, t = lane & 15;
    const float scale = 0.115470054f;  // 1/sqrt(75)
    const int dbase = g * 75 + t;

    float q[5];
    #pragma unroll
    for (int r = 0; r < 5; ++r) {
        q[r] = (t + 16 * r < 75) ? Q[n * 320 + dbase + 16 * r] * scale : 0.f;
    }

    int idx[8]; float s[8];
    #pragma unroll
    for (int j = 0; j < 8; ++j) {
        idx[j] = mail[n * 8 + j];
        const u16* kr = HK + (long)idx[j] * 320 + dbase;
        float p = 0.f;
        #pragma unroll
        for (int r = 0; r < 5; ++r) p += q[r] * b2f(kr[16 * r]);
        p += __shfl_xor(p, 8, 64);
        p += __shfl_xor(p, 4, 64);
        p += __shfl_xor(p, 2, 64);
        p += __shfl_xor(p, 1, 64);
        s[j] = p;
    }
    float mx = s[0];
    #pragma unroll
    for (int j = 1; j < 8; ++j) mx = fmaxf(mx, s[j]);
    float sum = 0.f;
    #pragma unroll
    for (int j = 0; j < 8; ++j) { s[j] = __expf(s[j] - mx); sum += s[j]; }
    const float inv = 1.f / sum;

    float o[5];
    #pragma unroll
    for (int r = 0; r < 5; ++r) o[r] = FV[n * 320 + dbase + 16 * r];  // softmax sums to 1
    #pragma unroll
    for (int j = 0; j < 8; ++j) {
        const float pj = s[j] * inv;
        const u16* vr = HV + (long)idx[j] * 320 + dbase;
        #pragma unroll
        for (int r = 0; r < 5; ++r) o[r] += pj * b2f(vr[16 * r]);
    }
    #pragma unroll
    for (int r = 0; r < 5; ++r)
        if (t + 16 * r < 75) Ob[n * 320 + dbase + 16 * r] = f2b(o[r]);
    if (lane < 20) Ob[n * 320 + 300 + lane] = 0;   // zero pad cols
}

// ---------------- mb = bf16( f_h[src[e]] - h[e^1] ) ----------------
__global__ void mb_k(const float* __restrict__ fh, const u16* __restrict__ hb,
                     const int* __restrict__ srcidx, u16* __restrict__ mb)
{
    long id = (long)blockIdx.x * blockDim.x + threadIdx.x;  // E*40 threads
    long e = id / 40;
    int c8 = (int)(id % 40) * 8;
    int sidx = srcidx[e];
    const float* fr = fh + (long)sidx * 320 + c8;
    const u16* hr = hb + (e ^ 1) * 320 + c8;
    u32 w[4];
    #pragma unroll
    for (int p = 0; p < 4; ++p) {
        u16 lo = f2b(fr[2 * p]     - b2f(hr[2 * p]));
        u16 hi = f2b(fr[2 * p + 1] - b2f(hr[2 * p + 1]));
        w[p] = (u32)lo | ((u32)hi << 16);
    }
    u32* d = (u32*)(mb + e * 320 + c8);
    d[0] = w[0]; d[1] = w[1]; d[2] = w[2]; d[3] = w[3];
}

// ---------------- build concat A = [mail_sum | f_h | f] (bf16, N x 960) ----------------
__global__ __launch_bounds__(256) void concat_k(
    const u16* __restrict__ hb, const float* __restrict__ fh,
    const float* __restrict__ f, const int* __restrict__ mail,
    u16* __restrict__ Acat)
{
    const long n = blockIdx.x;
    int m[8];
    #pragma unroll
    for (int j = 0; j < 8; ++j) m[j] = mail[n * 8 + j];
    for (int c = threadIdx.x; c < 960; c += 256) {
        float v;
        if (c < 300) {
            float s = 0.f;
            #pragma unroll
            for (int j = 0; j < 8; ++j) s += b2f(hb[(long)m[j] * 320 + c]);
            v = s;
        } else if (c < 600) v = fh[n * 320 + (c - 300)];
        else if (c < 900) v = f[n * 300 + (c - 600)];
        else v = 0.f;
        Acat[n * 960 + c] = f2b(v);
    }
}

extern "C" void kernel_launch(void* const* d_in, const int* in_sizes, int n_in,
                              void* d_out, int out_size, void* d_ws, size_t ws_size,
                              hipStream_t stream)
{
    const int N = N_NODES, E = E_EDGES;
    const float* f    = (const float*)d_in[0];
    const float* x    = (const float*)d_in[1];
    const int*   mail = (const int*)d_in[2];
    const int*   srcx = (const int*)d_in[3];
    const float* Wq = (const float*)d_in[4];   const float* bq = (const float*)d_in[5];
    const float* Wk = (const float*)d_in[6];   const float* bk = (const float*)d_in[7];
    const float* Wv = (const float*)d_in[8];   const float* bv = (const float*)d_in[9];
    const float* Wo = (const float*)d_in[10];  const float* bo = (const float*)d_in[11];
    const float* Wmp = (const float*)d_in[12]; const float* bmp = (const float*)d_in[13];
    const float* Wlast = (const float*)d_in[14]; const float* blast = (const float*)d_in[15];
    float* out = (float*)d_out;

    char* ws = (char*)d_ws;
    size_t off = 0;
    auto alloc = [&](size_t b) -> void* {
        void* p = ws + off; off += (b + 255) & ~(size_t)255; return p;
    };
    u16* hb   = (u16*)alloc((size_t)E * DP * 2);   // h (bf16, padded)
    u16* HKb  = (u16*)alloc((size_t)E * DP * 2);   // HK; reused as mb
    u16* HVb  = (u16*)alloc((size_t)E * DP * 2);   // HV; reused as Acat
    float* Qf = (float*)alloc((size_t)N * DP * 4);
    float* FV = (float*)alloc((size_t)N * DP * 4);
    float* fh = (float*)alloc((size_t)N * DP * 4);
    u16* fhb  = (u16*)alloc((size_t)N * DP * 2);
    u16* Ob   = (u16*)alloc((size_t)N * DP * 2);
    u16* WqB  = (u16*)alloc(320 * 320 * 2);
    u16* WkB  = (u16*)alloc(320 * 320 * 2);
    u16* WvB  = (u16*)alloc(320 * 320 * 2);
    u16* WoB  = (u16*)alloc(320 * 320 * 2);
    u16* Wm0B = (u16*)alloc(320 * 320 * 2);
    u16* Wm1B = (u16*)alloc(320 * 320 * 2);
    u16* WcatB = (u16*)alloc((size_t)KCAT * 320 * 2);
    // optional bf16 copy of x (saves the 314MB f32 re-read in the h-update epilogue)
    u16* xb = nullptr;
    if (ws_size >= off + (size_t)E * DP * 2) xb = (u16*)alloc((size_t)E * DP * 2);

    // ---- weights: transpose + pad + bf16 ----
    {
        long tot = (long)320 * 320;
        int blks = (int)((tot + 255) / 256);
        convT_k<<<blks, 256, 0, stream>>>(Wq, 300, 300, WqB, 320, tot);
        convT_k<<<blks, 256, 0, stream>>>(Wk, 300, 300, WkB, 320, tot);
        convT_k<<<blks, 256, 0, stream>>>(Wv, 300, 300, WvB, 320, tot);
        convT_k<<<blks, 256, 0, stream>>>(Wo, 300, 300, WoB, 320, tot);
        convT_k<<<blks, 256, 0, stream>>>(Wmp,          300, 300, Wm0B, 320, tot);
        convT_k<<<blks, 256, 0, stream>>>(Wmp + 90000,  300, 300, Wm1B, 320, tot);
        long totc = (long)320 * KCAT;
        convT_k<<<(int)((totc + 255) / 256), 256, 0, stream>>>(Wlast, 900, 300, WcatB, KCAT, totc);
    }
    // ---- activations: h0 = bf16(x) (+xb copy), fh0 = bf16(f) ----
    {
        long totE = (long)E * (DP / 8);
        padconv_k<<<(int)((totE + 255) / 256), 256, 0, stream>>>(x, 300, hb, xb, DP, totE);
        long totN = (long)N * (DP / 8);
        padconv_k<<<(int)((totN + 255) / 256), 256, 0, stream>>>(f, 300, fhb, nullptr, DP, totN);
    }

    for (int it = 0; it < 2; ++it) {
        const u16* WmB = it ? Wm1B : Wm0B;
        const float* bmpi = bmp + it * 300;
        // Q = f_h @ Wq + bq            (f32)
        gemm_k<<<N / 64, 256, 0, stream>>>(fhb, 320, WqB, bq, nullptr, nullptr, Qf, 320, 320, nullptr, 0);
        // FV = f_h @ Wv + bv           (f32)
        gemm_k<<<N / 64, 256, 0, stream>>>(fhb, 320, WvB, bv, nullptr, nullptr, FV, 320, 320, nullptr, 0);
        // HK = h @ Wk + bk             (bf16)
        gemm_k<<<E / 64, 256, 0, stream>>>(hb, 320, WkB, bk, nullptr, nullptr, nullptr, 0, 0, HKb, 0);
        // HV = h @ Wv                  (bf16)
        gemm_k<<<E / 64, 256, 0, stream>>>(hb, 320, WvB, nullptr, nullptr, nullptr, nullptr, 0, 0, HVb, 0);
        // attention -> Ob (bf16)
        attn_k<<<N / 4, 256, 0, stream>>>(Qf, FV, HKb, HVb, mail, Ob);
        // f_h = O @ Wo + bo            (f32 + bf16)
        gemm_k<<<N / 64, 256, 0, stream>>>(Ob, 320, WoB, bo, nullptr, nullptr, fh, 320, 320, fhb, 0);
        // mb = bf16(f_h[src] - h[e^1])   (reuse HKb)
        mb_k<<<(int)(((long)E * 40) / 256), 256, 0, stream>>>(fh, hb, srcx, HKb);
        // h = relu(x + mb @ Wmp + bmp)  (bf16)
        // x-term: bf16 xb if ws allows; else iter0 reads hb (==bf16(x), alias-safe), iter1 reads f32 x
        const float* a2f = (xb || it == 0) ? nullptr : x;
        const u16*   a2b = xb ? xb : (it == 0 ? hb : nullptr);
        gemm_k<<<E / 64, 256, 0, stream>>>(HKb, 320, WmB, bmpi, a2f, a2b, nullptr, 0, 0, hb, 1);
    }

    // Acat = [mail_sum | f_h | f]  (reuse HVb)
    concat_k<<<N, 256, 0, stream>>>(hb, fh, f, mail, HVb);
    // out = Acat @ Wlast + blast   (f32, stride 300)
    gemm_k<<<N / 64, 256, 0, stream>>>(HVb, KCAT, WcatB, blast, nullptr, nullptr, out, 300, 300, nullptr, 0);
}

// Round 3
// 2007.467 us; speedup vs baseline: 1.3119x; 1.1670x over previous
//
#include <hip/hip_runtime.h>

typedef unsigned short u16;
typedef unsigned int u32;
typedef __bf16 bf16x8 __attribute__((ext_vector_type(8)));
typedef float f32x4 __attribute__((ext_vector_type(4)));

#define N_NODES 32768
#define E_EDGES 262144
#define DP 320          // padded feature dim (300 -> 320)
#define KCAT 960        // padded concat K (900 -> 960)

__device__ __forceinline__ float b2f(u16 u) {
    union { u32 u; float f; } x; x.u = ((u32)u) << 16; return x.f;
}
__device__ __forceinline__ u16 f2b(float f) {
    union { float f; u32 u; } x; x.f = f;
    u32 r = x.u + 0x7FFF + ((x.u >> 16) & 1);
    return (u16)(r >> 16);
}

#define GLOAD16(g, l) \
    __builtin_amdgcn_global_load_lds((const __attribute__((address_space(1))) u32*)(g), \
                                     (__attribute__((address_space(3))) u32*)(l), 16, 0, 0)

// ---------------- weight transpose+pad+convert:  dst[n][k] = W[k][n] ----------------
__global__ void convT_k(const float* __restrict__ src, int R, int C,
                        u16* __restrict__ dst, int KP, long total) {
    long id = (long)blockIdx.x * blockDim.x + threadIdx.x;
    if (id >= total) return;
    int n = (int)(id / KP), k = (int)(id % KP);
    dst[id] = (k < R && n < C) ? f2b(src[(long)k * C + n]) : (u16)0;
}

// ---------------- activation pad+convert: f32 MxC -> bf16 MxCP (pad 0), dual dest ----------------
__global__ void padconv_k(const float* __restrict__ src, int C,
                          u16* __restrict__ dst, u16* __restrict__ dst2,
                          int CP, long total) {
    long id = (long)blockIdx.x * blockDim.x + threadIdx.x;
    if (id >= total) return;
    int cw = CP >> 3;
    long row = id / cw;
    int c8 = (int)(id % cw) * 8;
    u32 w[4];
    #pragma unroll
    for (int p = 0; p < 4; ++p) {
        int c0 = c8 + 2 * p, c1 = c0 + 1;
        u16 lo = (c0 < C) ? f2b(src[row * C + c0]) : (u16)0;
        u16 hi = (c1 < C) ? f2b(src[row * C + c1]) : (u16)0;
        w[p] = (u32)lo | ((u32)hi << 16);
    }
    u32* d = (u32*)(dst + row * CP + c8);
    d[0] = w[0]; d[1] = w[1]; d[2] = w[2]; d[3] = w[3];
    if (dst2) {
        u32* d2 = (u32*)(dst2 + row * CP + c8);
        d2[0] = w[0]; d2[1] = w[1]; d2[2] = w[2]; d2[3] = w[3];
    }
}

// ---------------- GEMM: C(Mx320) = A(MxKP bf16) * BT^T, BT is (320 x KP) n-major ----------------
// tile 64(M) x 320(N), BK=64. 4 waves; wave w owns cols [80w, 80w+80).
// A: double-buffered LDS via global_load_lds (XOR-swizzled source), ONE barrier/step.
// B: direct L2->register, software-pipelined one K-step ahead (bA/bB reg double-buffer).
// MFMA operands SWAPPED: lane holds out_row = fr*16+tl, out_cols = fc*16+thi*4+{0..3}
// -> vectorized epilogue (8B bf16 / 16B f32 stores per fragment).
template<int KP>
__global__ __launch_bounds__(256, 2) void gemm_k(
    const u16* __restrict__ A,
    const u16* __restrict__ BT,
    const float* __restrict__ bias,      // len >=300 or null
    const float* __restrict__ add2f,     // M x 300 f32 or null
    const u16*  __restrict__ add2b,      // M x 320 bf16 or null
    float* __restrict__ outF, int ostride, int ocols,   // or null
    u16* __restrict__ outB,              // M x 320 bf16 or null
    int relu)
{
    __shared__ u16 As[2][64 * 64];       // 16 KB total (2 x 8 KB)
    const int tid = threadIdx.x;
    const int w = tid >> 6, lane = tid & 63;
    const int tl = lane & 15, thi = lane >> 4;
    const int sx = tl & 7;               // read-side swizzle key (row&7)
    const long m0 = (long)blockIdx.x * 64;
    const int w_u = __builtin_amdgcn_readfirstlane(w);

    const int lr = lane >> 3;            // staging row within 8-row chunk
    const int lu = lane & 7;             // linear 16B slot
    // A staging: wave w stages rows [16w,16w+16); source col-unit = lu^lr (inverse swizzle)
    const u16* gA = A + (m0 + w * 16 + lr) * (long)KP + (lu ^ lr) * 8;
    // B frags: col = w*80 + fc*16 + tl, k-slice thi*8 folded in
    const u16* gBw = BT + ((long)(w * 80 + tl)) * KP + thi * 8;

    f32x4 acc[4][5];
    #pragma unroll
    for (int i = 0; i < 4; ++i)
        #pragma unroll
        for (int j = 0; j < 5; ++j) acc[i][j] = (f32x4)(0.f);

    const int nst = KP >> 6;
    bf16x8 bA[5][2], bB[5][2], a[4][2];

#define STAGEA(kt1) { const int bs_ = (kt1) & 1; const long ko_ = (long)(kt1) << 6; \
    GLOAD16(gA + ko_,                &As[bs_][(w_u * 2 + 0) * 512]); \
    GLOAD16(gA + 8 * (long)KP + ko_, &As[bs_][(w_u * 2 + 1) * 512]); }

#define LOADB(bq, kt1) { const long ko_ = (long)(kt1) << 6; \
    _Pragma("unroll") for (int fc = 0; fc < 5; ++fc) \
      _Pragma("unroll") for (int ks = 0; ks < 2; ++ks) \
        bq[fc][ks] = *(const bf16x8*)(gBw + (long)fc * 16 * KP + ko_ + ks * 32); }

#define READA(kt0) { const u16* ab_ = &As[(kt0) & 1][0]; \
    _Pragma("unroll") for (int fr = 0; fr < 4; ++fr) \
      _Pragma("unroll") for (int ks = 0; ks < 2; ++ks) \
        a[fr][ks] = *(const bf16x8*)&ab_[(fr * 16 + tl) * 64 + (((ks * 4 + thi) ^ sx) * 8)]; }

#define DOMFMA(bq) { _Pragma("unroll") for (int fr = 0; fr < 4; ++fr) \
    _Pragma("unroll") for (int fc = 0; fc < 5; ++fc) \
      _Pragma("unroll") for (int ks = 0; ks < 2; ++ks) \
        acc[fr][fc] = __builtin_amdgcn_mfma_f32_16x16x32_bf16(bq[fc][ks], a[fr][ks], acc[fr][fc], 0, 0, 0); }

    STAGEA(0); LOADB(bA, 0);
    __syncthreads();
    int kt = 0;
    for (;;) {
        if (kt + 1 < nst) { STAGEA(kt + 1); LOADB(bB, kt + 1); }
        READA(kt); DOMFMA(bA);
        __syncthreads();
        if (++kt >= nst) break;
        if (kt + 1 < nst) { STAGEA(kt + 1); LOADB(bA, kt + 1); }
        READA(kt); DOMFMA(bB);
        __syncthreads();
        if (++kt >= nst) break;
    }
#undef STAGEA
#undef LOADB
#undef READA
#undef DOMFMA

    // ---- epilogue: lane holds row = m0+fr*16+tl, 4 consecutive cols at fc*16+thi*4 ----
    #pragma unroll
    for (int fr = 0; fr < 4; ++fr) {
        const long row = m0 + fr * 16 + tl;
        #pragma unroll
        for (int fc = 0; fc < 5; ++fc) {
            const int c0 = w * 80 + fc * 16 + thi * 4;
            f32x4 v = acc[fr][fc];
            if (bias && c0 < 300) {
                const float4 bs = *(const float4*)&bias[c0];
                v[0] += bs.x; v[1] += bs.y; v[2] += bs.z; v[3] += bs.w;
            }
            if (add2f && c0 < 300) {
                const float4 xv = *(const float4*)&add2f[row * 300 + c0];
                v[0] += xv.x; v[1] += xv.y; v[2] += xv.z; v[3] += xv.w;
            }
            if (add2b) {
                const ushort4 xb = *(const ushort4*)&add2b[row * 320 + c0];
                v[0] += b2f(xb.x); v[1] += b2f(xb.y); v[2] += b2f(xb.z); v[3] += b2f(xb.w);
            }
            if (relu) {
                v[0] = fmaxf(v[0], 0.f); v[1] = fmaxf(v[1], 0.f);
                v[2] = fmaxf(v[2], 0.f); v[3] = fmaxf(v[3], 0.f);
            }
            if (outF && c0 < ocols)
                *(float4*)&outF[row * (long)ostride + c0] = make_float4(v[0], v[1], v[2], v[3]);
            if (outB) {
                uint2 p;
                p.x = (u32)f2b(v[0]) | ((u32)f2b(v[1]) << 16);
                p.y = (u32)f2b(v[2]) | ((u32)f2b(v[3]) << 16);
                *(uint2*)&outB[row * 320 + c0] = p;
            }
        }
    }
}

// ---------------- fused 8-key 4-head attention, one wave per node ----------------
__global__ __launch_bounds__(256) void attn_k(
    const float* __restrict__ Q, const float* __restrict__ FV,
    const u16* __restrict__ HK, const u16* __restrict__ HV,
    const int* __restrict__ mail, u16* __restrict__ Ob)
{
    const int tid = threadIdx.x;
    const long n = (long)blockIdx.x * 4 + (tid >> 6);
    const int lane = tid & 63, g = lane >> 4, t = lane & 15;
    const float scale = 0.115470054f;  // 1/sqrt(75)
    const int dbase = g * 75 + t;

    float q[5];
    #pragma unroll
    for (int r = 0; r < 5; ++r) {
        q[r] = (t + 16 * r < 75) ? Q[n * 320 + dbase + 16 * r] * scale : 0.f;
    }

    int idx[8]; float s[8];
    #pragma unroll
    for (int j = 0; j < 8; ++j) {
        idx[j] = mail[n * 8 + j];
        const u16* kr = HK + (long)idx[j] * 320 + dbase;
        float p = 0.f;
        #pragma unroll
        for (int r = 0; r < 5; ++r) p += q[r] * b2f(kr[16 * r]);
        p += __shfl_xor(p, 8, 64);
        p += __shfl_xor(p, 4, 64);
        p += __shfl_xor(p, 2, 64);
        p += __shfl_xor(p, 1, 64);
        s[j] = p;
    }
    float mx = s[0];
    #pragma unroll
    for (int j = 1; j < 8; ++j) mx = fmaxf(mx, s[j]);
    float sum = 0.f;
    #pragma unroll
    for (int j = 0; j < 8; ++j) { s[j] = __expf(s[j] - mx); sum += s[j]; }
    const float inv = 1.f / sum;

    float o[5];
    #pragma unroll
    for (int r = 0; r < 5; ++r) o[r] = FV[n * 320 + dbase + 16 * r];  // softmax sums to 1
    #pragma unroll
    for (int j = 0; j < 8; ++j) {
        const float pj = s[j] * inv;
        const u16* vr = HV + (long)idx[j] * 320 + dbase;
        #pragma unroll
        for (int r = 0; r < 5; ++r) o[r] += pj * b2f(vr[16 * r]);
    }
    #pragma unroll
    for (int r = 0; r < 5; ++r)
        if (t + 16 * r < 75) Ob[n * 320 + dbase + 16 * r] = f2b(o[r]);
    if (lane < 20) Ob[n * 320 + 300 + lane] = 0;   // zero pad cols
}

// ---------------- mb = bf16( fhb[src[e]] - hb[e^1] ), vectorized x8 ----------------
__global__ void mb_k(const u16* __restrict__ fhb, const u16* __restrict__ hb,
                     const int* __restrict__ srcidx, u16* __restrict__ mb)
{
    long id = (long)blockIdx.x * blockDim.x + threadIdx.x;  // E*40 threads
    long e = id / 40;
    int c8 = (int)(id % 40) * 8;
    int sidx = srcidx[e];
    const uint4 fv = *(const uint4*)&fhb[(long)sidx * 320 + c8];
    const uint4 hv = *(const uint4*)&hb[(e ^ 1) * 320 + c8];
    const u32 fa[4] = {fv.x, fv.y, fv.z, fv.w};
    const u32 ha[4] = {hv.x, hv.y, hv.z, hv.w};
    u32 o[4];
    #pragma unroll
    for (int p = 0; p < 4; ++p) {
        u16 lo = f2b(b2f((u16)(fa[p] & 0xFFFF))  - b2f((u16)(ha[p] & 0xFFFF)));
        u16 hi = f2b(b2f((u16)(fa[p] >> 16))     - b2f((u16)(ha[p] >> 16)));
        o[p] = (u32)lo | ((u32)hi << 16);
    }
    uint4* d = (uint4*)(mb + e * 320 + c8);
    *d = make_uint4(o[0], o[1], o[2], o[3]);
}

// ---------------- build concat A = [mail_sum | f_h | f] (bf16, N x 960) ----------------
__global__ __launch_bounds__(256) void concat_k(
    const u16* __restrict__ hb, const float* __restrict__ fh,
    const float* __restrict__ f, const int* __restrict__ mail,
    u16* __restrict__ Acat)
{
    const long n = blockIdx.x;
    int m[8];
    #pragma unroll
    for (int j = 0; j < 8; ++j) m[j] = mail[n * 8 + j];
    for (int c = threadIdx.x; c < 960; c += 256) {
        float v;
        if (c < 300) {
            float s = 0.f;
            #pragma unroll
            for (int j = 0; j < 8; ++j) s += b2f(hb[(long)m[j] * 320 + c]);
            v = s;
        } else if (c < 600) v = fh[n * 320 + (c - 300)];
        else if (c < 900) v = f[n * 300 + (c - 600)];
        else v = 0.f;
        Acat[n * 960 + c] = f2b(v);
    }
}

extern "C" void kernel_launch(void* const* d_in, const int* in_sizes, int n_in,
                              void* d_out, int out_size, void* d_ws, size_t ws_size,
                              hipStream_t stream)
{
    const int N = N_NODES, E = E_EDGES;
    const float* f    = (const float*)d_in[0];
    const float* x    = (const float*)d_in[1];
    const int*   mail = (const int*)d_in[2];
    const int*   srcx = (const int*)d_in[3];
    const float* Wq = (const float*)d_in[4];   const float* bq = (const float*)d_in[5];
    const float* Wk = (const float*)d_in[6];   const float* bk = (const float*)d_in[7];
    const float* Wv = (const float*)d_in[8];   const float* bv = (const float*)d_in[9];
    const float* Wo = (const float*)d_in[10];  const float* bo = (const float*)d_in[11];
    const float* Wmp = (const float*)d_in[12]; const float* bmp = (const float*)d_in[13];
    const float* Wlast = (const float*)d_in[14]; const float* blast = (const float*)d_in[15];
    float* out = (float*)d_out;

    char* ws = (char*)d_ws;
    size_t off = 0;
    auto alloc = [&](size_t b) -> void* {
        void* p = ws + off; off += (b + 255) & ~(size_t)255; return p;
    };
    u16* hb   = (u16*)alloc((size_t)E * DP * 2);   // h (bf16, padded)
    u16* HKb  = (u16*)alloc((size_t)E * DP * 2);   // HK; reused as mb
    u16* HVb  = (u16*)alloc((size_t)E * DP * 2);   // HV; reused as Acat
    float* Qf = (float*)alloc((size_t)N * DP * 4);
    float* FV = (float*)alloc((size_t)N * DP * 4);
    float* fh = (float*)alloc((size_t)N * DP * 4);
    u16* fhb  = (u16*)alloc((size_t)N * DP * 2);
    u16* Ob   = (u16*)alloc((size_t)N * DP * 2);
    u16* WqB  = (u16*)alloc(320 * 320 * 2);
    u16* WkB  = (u16*)alloc(320 * 320 * 2);
    u16* WvB  = (u16*)alloc(320 * 320 * 2);
    u16* WoB  = (u16*)alloc(320 * 320 * 2);
    u16* Wm0B = (u16*)alloc(320 * 320 * 2);
    u16* Wm1B = (u16*)alloc(320 * 320 * 2);
    u16* WcatB = (u16*)alloc((size_t)KCAT * 320 * 2);
    // optional bf16 copy of x (saves the f32 re-read in the h-update epilogue)
    u16* xb = nullptr;
    if (ws_size >= off + (size_t)E * DP * 2) xb = (u16*)alloc((size_t)E * DP * 2);

    // ---- weights: transpose + pad + bf16 ----
    {
        long tot = (long)320 * 320;
        int blks = (int)((tot + 255) / 256);
        convT_k<<<blks, 256, 0, stream>>>(Wq, 300, 300, WqB, 320, tot);
        convT_k<<<blks, 256, 0, stream>>>(Wk, 300, 300, WkB, 320, tot);
        convT_k<<<blks, 256, 0, stream>>>(Wv, 300, 300, WvB, 320, tot);
        convT_k<<<blks, 256, 0, stream>>>(Wo, 300, 300, WoB, 320, tot);
        convT_k<<<blks, 256, 0, stream>>>(Wmp,          300, 300, Wm0B, 320, tot);
        convT_k<<<blks, 256, 0, stream>>>(Wmp + 90000,  300, 300, Wm1B, 320, tot);
        long totc = (long)320 * KCAT;
        convT_k<<<(int)((totc + 255) / 256), 256, 0, stream>>>(Wlast, 900, 300, WcatB, KCAT, totc);
    }
    // ---- activations: h0 = bf16(x) (+xb copy), fh0 = bf16(f) ----
    {
        long totE = (long)E * (DP / 8);
        padconv_k<<<(int)((totE + 255) / 256), 256, 0, stream>>>(x, 300, hb, xb, DP, totE);
        long totN = (long)N * (DP / 8);
        padconv_k<<<(int)((totN + 255) / 256), 256, 0, stream>>>(f, 300, fhb, nullptr, DP, totN);
    }

    for (int it = 0; it < 2; ++it) {
        const u16* WmB = it ? Wm1B : Wm0B;
        const float* bmpi = bmp + it * 300;
        // Q = f_h @ Wq + bq            (f32)
        gemm_k<320><<<N / 64, 256, 0, stream>>>(fhb, WqB, bq, nullptr, nullptr, Qf, 320, 320, nullptr, 0);
        // FV = f_h @ Wv + bv           (f32)
        gemm_k<320><<<N / 64, 256, 0, stream>>>(fhb, WvB, bv, nullptr, nullptr, FV, 320, 320, nullptr, 0);
        // HK = h @ Wk + bk             (bf16)
        gemm_k<320><<<E / 64, 256, 0, stream>>>(hb, WkB, bk, nullptr, nullptr, nullptr, 0, 0, HKb, 0);
        // HV = h @ Wv                  (bf16)
        gemm_k<320><<<E / 64, 256, 0, stream>>>(hb, WvB, nullptr, nullptr, nullptr, nullptr, 0, 0, HVb, 0);
        // attention -> Ob (bf16)
        attn_k<<<N / 4, 256, 0, stream>>>(Qf, FV, HKb, HVb, mail, Ob);
        // f_h = O @ Wo + bo            (f32 + bf16)
        gemm_k<320><<<N / 64, 256, 0, stream>>>(Ob, WoB, bo, nullptr, nullptr, fh, 320, 320, fhb, 0);
        // mb = bf16(fhb[src] - hb[e^1])   (reuse HKb)
        mb_k<<<(int)(((long)E * 40) / 256), 256, 0, stream>>>(fhb, hb, srcx, HKb);
        // h = relu(x + mb @ Wmp + bmp)  (bf16)
        const float* a2f = (xb || it == 0) ? nullptr : x;
        const u16*   a2b = xb ? xb : (it == 0 ? hb : nullptr);
        gemm_k<320><<<E / 64, 256, 0, stream>>>(HKb, WmB, bmpi, a2f, a2b, nullptr, 0, 0, hb, 1);
    }

    // Acat = [mail_sum | f_h | f]  (reuse HVb)
    concat_k<<<N, 256, 0, stream>>>(hb, fh, f, mail, HVb);
    // out = Acat @ Wlast + blast   (f32, stride 300)
    gemm_k<960><<<N / 64, 256, 0, stream>>>(HVb, WcatB, blast, nullptr, nullptr, out, 300, 300, nullptr, 0);
}

// Round 4
// 1850.580 us; speedup vs baseline: 1.4232x; 1.0848x over previous
//
#include <hip/hip_runtime.h>

typedef unsigned short u16;
typedef unsigned int u32;
typedef __bf16 bf16x8 __attribute__((ext_vector_type(8)));
typedef float f32x4 __attribute__((ext_vector_type(4)));

#define N_NODES 32768
#define E_EDGES 262144
#define DP 320          // padded feature dim (300 -> 320)
#define KCAT 960        // padded concat K (900 -> 960)

__device__ __forceinline__ float b2f(u16 u) {
    union { u32 u; float f; } x; x.u = ((u32)u) << 16; return x.f;
}
__device__ __forceinline__ u16 f2b(float f) {
    union { float f; u32 u; } x; x.f = f;
    u32 r = x.u + 0x7FFF + ((x.u >> 16) & 1);
    return (u16)(r >> 16);
}
__device__ __forceinline__ u32 bsub2(u32 a, u32 b) {
    float lo = b2f((u16)(a & 0xFFFF)) - b2f((u16)(b & 0xFFFF));
    float hi = b2f((u16)(a >> 16))    - b2f((u16)(b >> 16));
    return (u32)f2b(lo) | ((u32)f2b(hi) << 16);
}

#define GLOAD16(g, l) \
    __builtin_amdgcn_global_load_lds((const __attribute__((address_space(1))) u32*)(g), \
                                     (__attribute__((address_space(3))) u32*)(l), 16, 0, 0)

// B: direct L2->register prefetch (per-wave, vmcnt-tracked; no barriers involved)
#define LOADB(bq, kt1) { const long ko_ = (long)(kt1) << 6; \
    _Pragma("unroll") for (int fc = 0; fc < 5; ++fc) \
      _Pragma("unroll") for (int ks = 0; ks < 2; ++ks) \
        bq[fc][ks] = *(const bf16x8*)(gBw + (long)fc * 16 * KP + ko_ + ks * 32); }

#define READA(lkt) { \
    _Pragma("unroll") for (int fr = 0; fr < 4; ++fr) \
      _Pragma("unroll") for (int ks = 0; ks < 2; ++ks) \
        a[fr][ks] = *(const bf16x8*)&As[(fr * 16 + tl) * 320 + ((((lkt) * 8 + ks * 4 + thi) ^ sx) * 8)]; }

#define DOMFMA(bq) { _Pragma("unroll") for (int fr = 0; fr < 4; ++fr) \
    _Pragma("unroll") for (int fc = 0; fc < 5; ++fc) \
      _Pragma("unroll") for (int ks = 0; ks < 2; ++ks) \
        acc[fr][fc] = __builtin_amdgcn_mfma_f32_16x16x32_bf16(bq[fc][ks], a[fr][ks], acc[fr][fc], 0, 0, 0); }

// ---------------- weight transpose+pad+convert:  dst[n][k] = W[k][n] ----------------
__global__ void convT_k(const float* __restrict__ src, int R, int C,
                        u16* __restrict__ dst, int KP_, long total) {
    long id = (long)blockIdx.x * blockDim.x + threadIdx.x;
    if (id >= total) return;
    int n = (int)(id / KP_), k = (int)(id % KP_);
    dst[id] = (k < R && n < C) ? f2b(src[(long)k * C + n]) : (u16)0;
}

// ---------------- activation pad+convert: f32 MxC -> bf16 MxCP (pad 0), dual dest ----------------
__global__ void padconv_k(const float* __restrict__ src, int C,
                          u16* __restrict__ dst, u16* __restrict__ dst2,
                          int CP, long total) {
    long id = (long)blockIdx.x * blockDim.x + threadIdx.x;
    if (id >= total) return;
    int cw = CP >> 3;
    long row = id / cw;
    int c8 = (int)(id % cw) * 8;
    u32 w[4];
    #pragma unroll
    for (int p = 0; p < 4; ++p) {
        int c0 = c8 + 2 * p, c1 = c0 + 1;
        u16 lo = (c0 < C) ? f2b(src[row * C + c0]) : (u16)0;
        u16 hi = (c1 < C) ? f2b(src[row * C + c1]) : (u16)0;
        w[p] = (u32)lo | ((u32)hi << 16);
    }
    u32* d = (u32*)(dst + row * CP + c8);
    d[0] = w[0]; d[1] = w[1]; d[2] = w[2]; d[3] = w[3];
    if (dst2) {
        u32* d2 = (u32*)(dst2 + row * CP + c8);
        d2[0] = w[0]; d2[1] = w[1]; d2[2] = w[2]; d2[3] = w[3];
    }
}

// ---------------- GEMM: C(Mx320) = A(MxKP bf16) * BT^T ----------------
// Whole A-tile (64 x 320-chunk, 40KB) staged ONCE via global_load_lds (swizzled source),
// ONE barrier per chunk; K-loop is barrier-free (A from LDS, B L2->reg double-buffered).
template<int KP>
__global__ __launch_bounds__(256, 2) void gemm_k(
    const u16* __restrict__ A,
    const u16* __restrict__ BT,
    const float* __restrict__ bias,      // len >=300 or null
    const float* __restrict__ add2f,     // M x 300 f32 or null
    const u16*  __restrict__ add2b,      // M x 320 bf16 or null
    float* __restrict__ outF, int ostride, int ocols,   // or null
    u16* __restrict__ outB,              // M x 320 bf16 or null
    int relu)
{
    __shared__ u16 As[64 * 320];         // 40 KB
    const int tid = threadIdx.x;
    const int w = tid >> 6, lane = tid & 63;
    const int tl = lane & 15, thi = lane >> 4;
    const int sx = tl & 7;
    const long m0 = (long)blockIdx.x * 64;
    const int w_u = __builtin_amdgcn_readfirstlane(w);

    const u16* gBw = BT + ((long)(w * 80 + tl)) * KP + thi * 8;

    f32x4 acc[4][5];
    #pragma unroll
    for (int i = 0; i < 4; ++i)
        #pragma unroll
        for (int j = 0; j < 5; ++j) acc[i][j] = (f32x4)(0.f);

    constexpr int NCH = KP / 320;
    constexpr int NST = KP >> 6;
    bf16x8 bA[5][2], bB[5][2], a[4][2];

    #pragma unroll
    for (int kb = 0; kb < NCH; ++kb) {
        if (kb) __syncthreads();         // all waves done reading previous chunk
        #pragma unroll
        for (int i = 0; i < 10; ++i) {   // stage 64x320 chunk: 2560 16B-chunks
            const int c = i * 256 + w_u * 64 + lane;
            const int r = c / 40, s = c - r * 40;
            GLOAD16(A + (m0 + r) * (long)KP + kb * 320 + ((s ^ (r & 7)) * 8),
                    &As[(i * 256 + w_u * 64) * 8]);
        }
        if (kb == 0) LOADB(bA, 0);
        __syncthreads();                 // drains vmcnt -> LDS ready
        #pragma unroll
        for (int lkt = 0; lkt < 5; ++lkt) {
            const int kt = kb * 5 + lkt;
            if (kt + 1 < NST) {
                if (kt & 1) { LOADB(bA, kt + 1); } else { LOADB(bB, kt + 1); }
            }
            READA(lkt);
            if (kt & 1) { DOMFMA(bB); } else { DOMFMA(bA); }
        }
    }

    // ---- epilogue: lane holds row = m0+fr*16+tl, 4 consecutive cols at w*80+fc*16+thi*4
    #pragma unroll
    for (int fr = 0; fr < 4; ++fr) {
        const long row = m0 + fr * 16 + tl;
        #pragma unroll
        for (int fc = 0; fc < 5; ++fc) {
            const int c0 = w * 80 + fc * 16 + thi * 4;
            f32x4 v = acc[fr][fc];
            if (bias && c0 < 300) {
                const float4 bs = *(const float4*)&bias[c0];
                v[0] += bs.x; v[1] += bs.y; v[2] += bs.z; v[3] += bs.w;
            }
            if (add2f && c0 < 300) {
                const float4 xv = *(const float4*)&add2f[row * 300 + c0];
                v[0] += xv.x; v[1] += xv.y; v[2] += xv.z; v[3] += xv.w;
            }
            if (add2b) {
                const ushort4 xb = *(const ushort4*)&add2b[row * 320 + c0];
                v[0] += b2f(xb.x); v[1] += b2f(xb.y); v[2] += b2f(xb.z); v[3] += b2f(xb.w);
            }
            if (relu) {
                v[0] = fmaxf(v[0], 0.f); v[1] = fmaxf(v[1], 0.f);
                v[2] = fmaxf(v[2], 0.f); v[3] = fmaxf(v[3], 0.f);
            }
            if (outF && c0 < ocols)
                *(float4*)&outF[row * (long)ostride + c0] = make_float4(v[0], v[1], v[2], v[3]);
            if (outB) {
                uint2 p;
                p.x = (u32)f2b(v[0]) | ((u32)f2b(v[1]) << 16);
                p.y = (u32)f2b(v[2]) | ((u32)f2b(v[3]) << 16);
                *(uint2*)&outB[row * 320 + c0] = p;
            }
        }
    }
}

// ---------------- dual-output GEMM (KP=320): waves 0-3 -> out0, 4-7 -> out1, shared A ----------------
__global__ __launch_bounds__(512, 2) void gemm2_k(
    const u16* __restrict__ A,
    const u16* __restrict__ BT0, const float* __restrict__ bias0, u16* __restrict__ out0,
    const u16* __restrict__ BT1, const float* __restrict__ bias1, u16* __restrict__ out1)
{
    constexpr int KP = 320;
    __shared__ u16 As[64 * 320];
    const int tid = threadIdx.x;
    const int wf = tid >> 6, lane = tid & 63;
    const int w = wf & 3, st = wf >> 2;
    const int tl = lane & 15, thi = lane >> 4;
    const int sx = tl & 7;
    const long m0 = (long)blockIdx.x * 64;
    const int wf_u = __builtin_amdgcn_readfirstlane(wf);

    const u16* BT = st ? BT1 : BT0;
    const float* bias = st ? bias1 : bias0;
    u16* outB = st ? out1 : out0;
    const u16* gBw = BT + ((long)(w * 80 + tl)) * KP + thi * 8;

    f32x4 acc[4][5];
    #pragma unroll
    for (int i = 0; i < 4; ++i)
        #pragma unroll
        for (int j = 0; j < 5; ++j) acc[i][j] = (f32x4)(0.f);

    bf16x8 bA[5][2], bB[5][2], a[4][2];

    #pragma unroll
    for (int i = 0; i < 5; ++i) {       // 512 threads x 5 = 2560 chunks
        const int c = i * 512 + wf_u * 64 + lane;
        const int r = c / 40, s = c - r * 40;
        GLOAD16(A + (m0 + r) * (long)KP + ((s ^ (r & 7)) * 8),
                &As[(i * 512 + wf_u * 64) * 8]);
    }
    LOADB(bA, 0);
    __syncthreads();
    #pragma unroll
    for (int lkt = 0; lkt < 5; ++lkt) {
        const int kt = lkt;
        if (kt + 1 < 5) {
            if (kt & 1) { LOADB(bA, kt + 1); } else { LOADB(bB, kt + 1); }
        }
        READA(lkt);
        if (kt & 1) { DOMFMA(bB); } else { DOMFMA(bA); }
    }

    #pragma unroll
    for (int fr = 0; fr < 4; ++fr) {
        const long row = m0 + fr * 16 + tl;
        #pragma unroll
        for (int fc = 0; fc < 5; ++fc) {
            const int c0 = w * 80 + fc * 16 + thi * 4;
            f32x4 v = acc[fr][fc];
            if (bias && c0 < 300) {
                const float4 bs = *(const float4*)&bias[c0];
                v[0] += bs.x; v[1] += bs.y; v[2] += bs.z; v[3] += bs.w;
            }
            uint2 p;
            p.x = (u32)f2b(v[0]) | ((u32)f2b(v[1]) << 16);
            p.y = (u32)f2b(v[2]) | ((u32)f2b(v[3]) << 16);
            *(uint2*)&outB[row * 320 + c0] = p;
        }
    }
}

// ---------------- h-update GEMM with fused mb staging: A = bf16(fhb[src[e]] - hb[e^1]) ----------------
__global__ __launch_bounds__(256, 2) void gemmmb_k(
    const u16* __restrict__ fhb, const u16* __restrict__ hb,
    const int* __restrict__ srcidx,
    const u16* __restrict__ BT, const float* __restrict__ bias,
    const float* __restrict__ add2f, const u16* __restrict__ add2b,
    u16* __restrict__ outB)
{
    constexpr int KP = 320;
    __shared__ u16 As[64 * 320];
    const int tid = threadIdx.x;
    const int w = tid >> 6, lane = tid & 63;
    const int tl = lane & 15, thi = lane >> 4;
    const int sx = tl & 7;
    const long m0 = (long)blockIdx.x * 64;
    const int w_u = __builtin_amdgcn_readfirstlane(w);

    const u16* gBw = BT + ((long)(w * 80 + tl)) * KP + thi * 8;

    f32x4 acc[4][5];
    #pragma unroll
    for (int i = 0; i < 4; ++i)
        #pragma unroll
        for (int j = 0; j < 5; ++j) acc[i][j] = (f32x4)(0.f);

    bf16x8 bA[5][2], bB[5][2], a[4][2];

    // reg-stage the mb tile (e^1 stays inside this 64-aligned block -> race-free)
    #pragma unroll
    for (int i = 0; i < 10; ++i) {
        const int c = i * 256 + w_u * 64 + lane;
        const int r = c / 40, s = c - r * 40;
        const int g = s ^ (r & 7);
        const long e = m0 + r;
        const int sidx = srcidx[e];
        const uint4 fv = *(const uint4*)&fhb[(long)sidx * 320 + g * 8];
        const uint4 hv = *(const uint4*)&hb[(e ^ 1) * 320 + g * 8];
        uint4 o;
        o.x = bsub2(fv.x, hv.x); o.y = bsub2(fv.y, hv.y);
        o.z = bsub2(fv.z, hv.z); o.w = bsub2(fv.w, hv.w);
        *(uint4*)&As[c * 8] = o;
    }
    LOADB(bA, 0);
    __syncthreads();
    #pragma unroll
    for (int lkt = 0; lkt < 5; ++lkt) {
        const int kt = lkt;
        if (kt + 1 < 5) {
            if (kt & 1) { LOADB(bA, kt + 1); } else { LOADB(bB, kt + 1); }
        }
        READA(lkt);
        if (kt & 1) { DOMFMA(bB); } else { DOMFMA(bA); }
    }

    #pragma unroll
    for (int fr = 0; fr < 4; ++fr) {
        const long row = m0 + fr * 16 + tl;
        #pragma unroll
        for (int fc = 0; fc < 5; ++fc) {
            const int c0 = w * 80 + fc * 16 + thi * 4;
            f32x4 v = acc[fr][fc];
            if (bias && c0 < 300) {
                const float4 bs = *(const float4*)&bias[c0];
                v[0] += bs.x; v[1] += bs.y; v[2] += bs.z; v[3] += bs.w;
            }
            if (add2f && c0 < 300) {
                const float4 xv = *(const float4*)&add2f[row * 300 + c0];
                v[0] += xv.x; v[1] += xv.y; v[2] += xv.z; v[3] += xv.w;
            }
            if (add2b) {
                const ushort4 xb = *(const ushort4*)&add2b[row * 320 + c0];
                v[0] += b2f(xb.x); v[1] += b2f(xb.y); v[2] += b2f(xb.z); v[3] += b2f(xb.w);
            }
            v[0] = fmaxf(v[0], 0.f); v[1] = fmaxf(v[1], 0.f);
            v[2] = fmaxf(v[2], 0.f); v[3] = fmaxf(v[3], 0.f);
            uint2 p;
            p.x = (u32)f2b(v[0]) | ((u32)f2b(v[1]) << 16);
            p.y = (u32)f2b(v[2]) | ((u32)f2b(v[3]) << 16);
            *(uint2*)&outB[row * 320 + c0] = p;
        }
    }
}

// ---------------- fused 8-key 4-head attention, one wave per node (bf16 Q/FV) ----------------
__global__ __launch_bounds__(256) void attn_k(
    const u16* __restrict__ Q, const u16* __restrict__ FV,
    const u16* __restrict__ HK, const u16* __restrict__ HV,
    const int* __restrict__ mail, u16* __restrict__ Ob)
{
    const int tid = threadIdx.x;
    const long n = (long)blockIdx.x * 4 + (tid >> 6);
    const int lane = tid & 63, g = lane >> 4, t = lane & 15;
    const float scale = 0.115470054f;  // 1/sqrt(75)
    const int dbase = g * 75 + t;

    float q[5];
    #pragma unroll
    for (int r = 0; r < 5; ++r)
        q[r] = (t + 16 * r < 75) ? b2f(Q[n * 320 + dbase + 16 * r]) * scale : 0.f;

    int idx[8]; float s[8];
    #pragma unroll
    for (int j = 0; j < 8; ++j) {
        idx[j] = mail[n * 8 + j];
        const u16* kr = HK + (long)idx[j] * 320 + dbase;
        float p = 0.f;
        #pragma unroll
        for (int r = 0; r < 5; ++r) p += q[r] * b2f(kr[16 * r]);
        p += __shfl_xor(p, 8, 64);
        p += __shfl_xor(p, 4, 64);
        p += __shfl_xor(p, 2, 64);
        p += __shfl_xor(p, 1, 64);
        s[j] = p;
    }
    float mx = s[0];
    #pragma unroll
    for (int j = 1; j < 8; ++j) mx = fmaxf(mx, s[j]);
    float sum = 0.f;
    #pragma unroll
    for (int j = 0; j < 8; ++j) { s[j] = __expf(s[j] - mx); sum += s[j]; }
    const float inv = 1.f / sum;

    float o[5];
    #pragma unroll
    for (int r = 0; r < 5; ++r) o[r] = b2f(FV[n * 320 + dbase + 16 * r]);  // softmax sums to 1
    #pragma unroll
    for (int j = 0; j < 8; ++j) {
        const float pj = s[j] * inv;
        const u16* vr = HV + (long)idx[j] * 320 + dbase;
        #pragma unroll
        for (int r = 0; r < 5; ++r) o[r] += pj * b2f(vr[16 * r]);
    }
    #pragma unroll
    for (int r = 0; r < 5; ++r)
        if (t + 16 * r < 75) Ob[n * 320 + dbase + 16 * r] = f2b(o[r]);
    if (lane < 20) Ob[n * 320 + 300 + lane] = 0;   // zero pad cols
}

// ---------------- build concat A = [mail_sum | f_h | f] (bf16, N x 960) ----------------
__global__ __launch_bounds__(256) void concat_k(
    const u16* __restrict__ hb, const float* __restrict__ fh,
    const float* __restrict__ f, const int* __restrict__ mail,
    u16* __restrict__ Acat)
{
    const long n = blockIdx.x;
    int m[8];
    #pragma unroll
    for (int j = 0; j < 8; ++j) m[j] = mail[n * 8 + j];
    for (int c = threadIdx.x; c < 960; c += 256) {
        float v;
        if (c < 300) {
            float s = 0.f;
            #pragma unroll
            for (int j = 0; j < 8; ++j) s += b2f(hb[(long)m[j] * 320 + c]);
            v = s;
        } else if (c < 600) v = fh[n * 320 + (c - 300)];
        else if (c < 900) v = f[n * 300 + (c - 600)];
        else v = 0.f;
        Acat[n * 960 + c] = f2b(v);
    }
}

extern "C" void kernel_launch(void* const* d_in, const int* in_sizes, int n_in,
                              void* d_out, int out_size, void* d_ws, size_t ws_size,
                              hipStream_t stream)
{
    const int N = N_NODES, E = E_EDGES;
    const float* f    = (const float*)d_in[0];
    const float* x    = (const float*)d_in[1];
    const int*   mail = (const int*)d_in[2];
    const int*   srcx = (const int*)d_in[3];
    const float* Wq = (const float*)d_in[4];   const float* bq = (const float*)d_in[5];
    const float* Wk = (const float*)d_in[6];   const float* bk = (const float*)d_in[7];
    const float* Wv = (const float*)d_in[8];   const float* bv = (const float*)d_in[9];
    const float* Wo = (const float*)d_in[10];  const float* bo = (const float*)d_in[11];
    const float* Wmp = (const float*)d_in[12]; const float* bmp = (const float*)d_in[13];
    const float* Wlast = (const float*)d_in[14]; const float* blast = (const float*)d_in[15];
    float* out = (float*)d_out;

    char* ws = (char*)d_ws;
    size_t off = 0;
    auto alloc = [&](size_t b) -> void* {
        void* p = ws + off; off += (b + 255) & ~(size_t)255; return p;
    };
    u16* hb   = (u16*)alloc((size_t)E * DP * 2);   // h (bf16, padded)
    u16* HKb  = (u16*)alloc((size_t)E * DP * 2);   // HK
    u16* HVb  = (u16*)alloc((size_t)E * DP * 2);   // HV; reused as Acat
    u16* Qb   = (u16*)alloc((size_t)N * DP * 2);
    u16* FVb  = (u16*)alloc((size_t)N * DP * 2);
    float* fh = (float*)alloc((size_t)N * DP * 4);
    u16* fhb  = (u16*)alloc((size_t)N * DP * 2);
    u16* Ob   = (u16*)alloc((size_t)N * DP * 2);
    u16* WqB  = (u16*)alloc(320 * 320 * 2);
    u16* WkB  = (u16*)alloc(320 * 320 * 2);
    u16* WvB  = (u16*)alloc(320 * 320 * 2);
    u16* WoB  = (u16*)alloc(320 * 320 * 2);
    u16* Wm0B = (u16*)alloc(320 * 320 * 2);
    u16* Wm1B = (u16*)alloc(320 * 320 * 2);
    u16* WcatB = (u16*)alloc((size_t)KCAT * 320 * 2);
    u16* xb = nullptr;
    if (ws_size >= off + (size_t)E * DP * 2) xb = (u16*)alloc((size_t)E * DP * 2);

    // ---- weights: transpose + pad + bf16 ----
    {
        long tot = (long)320 * 320;
        int blks = (int)((tot + 255) / 256);
        convT_k<<<blks, 256, 0, stream>>>(Wq, 300, 300, WqB, 320, tot);
        convT_k<<<blks, 256, 0, stream>>>(Wk, 300, 300, WkB, 320, tot);
        convT_k<<<blks, 256, 0, stream>>>(Wv, 300, 300, WvB, 320, tot);
        convT_k<<<blks, 256, 0, stream>>>(Wo, 300, 300, WoB, 320, tot);
        convT_k<<<blks, 256, 0, stream>>>(Wmp,          300, 300, Wm0B, 320, tot);
        convT_k<<<blks, 256, 0, stream>>>(Wmp + 90000,  300, 300, Wm1B, 320, tot);
        long totc = (long)320 * KCAT;
        convT_k<<<(int)((totc + 255) / 256), 256, 0, stream>>>(Wlast, 900, 300, WcatB, KCAT, totc);
    }
    // ---- activations: h0 = bf16(x) (+xb copy), fh0 = bf16(f) ----
    {
        long totE = (long)E * (DP / 8);
        padconv_k<<<(int)((totE + 255) / 256), 256, 0, stream>>>(x, 300, hb, xb, DP, totE);
        long totN = (long)N * (DP / 8);
        padconv_k<<<(int)((totN + 255) / 256), 256, 0, stream>>>(f, 300, fhb, nullptr, DP, totN);
    }

    for (int it = 0; it < 2; ++it) {
        const u16* WmB = it ? Wm1B : Wm0B;
        const float* bmpi = bmp + it * 300;
        // Q = f_h@Wq+bq ; FV = f_h@Wv+bv   (fused, bf16 out)
        gemm2_k<<<N / 64, 512, 0, stream>>>(fhb, WqB, bq, Qb, WvB, bv, FVb);
        // HK = h@Wk+bk ; HV = h@Wv         (fused, bf16 out)
        gemm2_k<<<E / 64, 512, 0, stream>>>(hb, WkB, bk, HKb, WvB, nullptr, HVb);
        // attention -> Ob (bf16)
        attn_k<<<N / 4, 256, 0, stream>>>(Qb, FVb, HKb, HVb, mail, Ob);
        // f_h = O @ Wo + bo            (f32 + bf16)
        gemm_k<320><<<N / 64, 256, 0, stream>>>(Ob, WoB, bo, nullptr, nullptr, fh, 320, 320, fhb, 0);
        // h = relu(x + (fhb[src]-hb[e^1]) @ Wmp + bmp)   (mb fused into staging)
        const float* a2f = (xb || it == 0) ? nullptr : x;
        const u16*   a2b = xb ? xb : (it == 0 ? hb : nullptr);
        gemmmb_k<<<E / 64, 256, 0, stream>>>(fhb, hb, srcx, WmB, bmpi, a2f, a2b, hb);
    }

    // Acat = [mail_sum | f_h | f]  (reuse HVb)
    concat_k<<<N, 256, 0, stream>>>(hb, fh, f, mail, HVb);
    // out = Acat @ Wlast + blast   (f32, stride 300)
    gemm_k<960><<<N / 64, 256, 0, stream>>>(HVb, WcatB, blast, nullptr, nullptr, out, 300, 300, nullptr, 0);
}

// Round 5
// 1710.358 us; speedup vs baseline: 1.5398x; 1.0820x over previous
//
#include <hip/hip_runtime.h>

typedef unsigned short u16;
typedef unsigned int u32;
typedef __bf16 bf16x8 __attribute__((ext_vector_type(8)));
typedef float f32x4 __attribute__((ext_vector_type(4)));

#define N_NODES 32768
#define E_EDGES 262144
#define DP 320          // padded feature dim (300 -> 320)
#define KCAT 960        // padded concat K (900 -> 960)
#define BH_U16 52480    // one 160-col half of swizzled B: 160*328 u16

__device__ __forceinline__ float b2f(u16 u) {
    union { u32 u; float f; } x; x.u = ((u32)u) << 16; return x.f;
}
__device__ __forceinline__ u16 f2b(float f) {
    union { float f; u32 u; } x; x.f = f;
    u32 r = x.u + 0x7FFF + ((x.u >> 16) & 1);
    return (u16)(r >> 16);
}
__device__ __forceinline__ u32 bsub2(u32 a, u32 b) {
    float lo = b2f((u16)(a & 0xFFFF)) - b2f((u16)(b & 0xFFFF));
    float hi = b2f((u16)(a >> 16))    - b2f((u16)(b >> 16));
    return (u32)f2b(lo) | ((u32)f2b(hi) << 16);
}

#define GLOAD16(g, l) \
    __builtin_amdgcn_global_load_lds((const __attribute__((address_space(1))) u32*)(g), \
                                     (__attribute__((address_space(3))) u32*)(l), 16, 0, 0)

// ---------------- plain weight transpose (for Wcat / old gemm path) ----------------
__global__ void convT_k(const float* __restrict__ src, int R, int C,
                        u16* __restrict__ dst, int KP_, long total) {
    long id = (long)blockIdx.x * blockDim.x + threadIdx.x;
    if (id >= total) return;
    int n = (int)(id / KP_), k = (int)(id % KP_);
    dst[id] = (k < R && n < C) ? f2b(src[(long)k * C + n]) : (u16)0;
}

// ---------------- swizzled+padded weight build for egemm: dst[h][r][c], c in [0,328)
// value = W[c][h*160+r] (k=c), pad 0 for c>=300 or n>=300.
__global__ void convTswz_k(const float* __restrict__ src, u16* __restrict__ dst) {
    int id = blockIdx.x * 256 + threadIdx.x;
    if (id >= 2 * 160 * 328) return;
    int h = id / BH_U16, rem = id % BH_U16;
    int r = rem / 328, c = rem % 328;
    int n = h * 160 + r;
    dst[id] = (c < 300 && n < 300) ? f2b(src[(long)c * 300 + n]) : (u16)0;
}

// ---------------- activation pad+convert: f32 MxC -> bf16 MxCP (pad 0), dual dest ----------------
__global__ void padconv_k(const float* __restrict__ src, int C,
                          u16* __restrict__ dst, u16* __restrict__ dst2,
                          int CP, long total) {
    long id = (long)blockIdx.x * blockDim.x + threadIdx.x;
    if (id >= total) return;
    int cw = CP >> 3;
    long row = id / cw;
    int c8 = (int)(id % cw) * 8;
    u32 w[4];
    #pragma unroll
    for (int p = 0; p < 4; ++p) {
        int c0 = c8 + 2 * p, c1 = c0 + 1;
        u16 lo = (c0 < C) ? f2b(src[row * C + c0]) : (u16)0;
        u16 hi = (c1 < C) ? f2b(src[row * C + c1]) : (u16)0;
        w[p] = (u32)lo | ((u32)hi << 16);
    }
    u32* d = (u32*)(dst + row * CP + c8);
    d[0] = w[0]; d[1] = w[1]; d[2] = w[2]; d[3] = w[3];
    if (dst2) {
        u32* d2 = (u32*)(dst2 + row * CP + c8);
        d2[0] = w[0]; d2[1] = w[1]; d2[2] = w[2]; d2[3] = w[3];
    }
}

// ================= shared compute macro for egemm kernels =================
// expects in scope: acc[4][5], Bs, ar0, br0, asl, thi8
#define TCOMP(KB, APTR) do { \
    bf16x8 av_[4], bb_[5]; \
    _Pragma("unroll") for (int fr = 0; fr < 4; ++fr) \
        av_[fr] = *(const bf16x8*)&(APTR)[ar0 + fr * 512 + asl]; \
    _Pragma("unroll") for (int fc = 0; fc < 5; ++fc) \
        bb_[fc] = *(const bf16x8*)&Bs[br0 + fc * 5248 + (KB) * 32 + thi8]; \
    _Pragma("unroll") for (int fr = 0; fr < 4; ++fr) \
        _Pragma("unroll") for (int fc = 0; fc < 5; ++fc) \
            acc[fr][fc] = __builtin_amdgcn_mfma_f32_16x16x32_bf16(bb_[fc], av_[fr], acc[fr][fc], 0, 0, 0); \
} while (0)

// ---------------- egemm: C(Mx320) = A(Mx320 bf16) @ W  (+bias), bf16 out ----------------
// block = 256 rows x 160 cols (blockIdx: m = b>>1, half = b&1). 8 waves: wr=wf&3 (M), wn=wf>>2 (N).
// B: full half-weight (100KB, padded 328-u16 rows) staged ONCE via gload_lds from pre-swizzled global.
// A: BK=32 chunks, TRIPLE-buffered LDS, counted vmcnt(2) + raw s_barrier (1 barrier/chunk).
__global__ __launch_bounds__(512, 2) void egemm_k(
    const u16* __restrict__ A, const u16* __restrict__ Bswz,
    const float* __restrict__ bias, u16* __restrict__ outB)
{
    __shared__ __attribute__((aligned(16))) u16 Bs[160 * 328];
    __shared__ __attribute__((aligned(16))) u16 As3[3][256 * 32];
    const int tid = threadIdx.x;
    const int wf = tid >> 6, lane = tid & 63;
    const int wr = wf & 3, wn = wf >> 2;
    const int tl = lane & 15, thi = lane >> 4;
    const int thi8 = thi * 8;
    const long m0 = (long)(blockIdx.x >> 1) * 256;
    const int n0 = (blockIdx.x & 1) * 160;
    const int wf_u = __builtin_amdgcn_readfirstlane(wf);
    const u16* Bsrc = Bswz + (blockIdx.x & 1) * BH_U16;

    // B prologue: 6560 16B chunks, linear src (pre-swizzled) -> linear LDS
    #pragma unroll
    for (int i = 0; i < 13; ++i) {
        int t = i * 512 + tid;
        if (t < 6560)
            GLOAD16(Bsrc + (long)t * 8, &Bs[(i * 512 + wf_u * 64) * 8]);
    }
    // A staging geometry: task t -> row t>>2, slot t&3; source col-unit g = s ^ ((row>>1)&3)
    const int r_ = tid >> 2;
    const int g_ = (tid & 3) ^ ((r_ >> 1) & 3);
    const u16* gA0 = A + (m0 + r_) * 320L + g_ * 8;
    const u16* gA1 = A + (m0 + 128 + r_) * 320L + g_ * 8;

#define ESTAGE(KB) { \
    GLOAD16(gA0 + (KB) * 32, &As3[(KB) % 3][wf_u * 64 * 8]); \
    GLOAD16(gA1 + (KB) * 32, &As3[(KB) % 3][(512 + wf_u * 64) * 8]); }

    ESTAGE(0); ESTAGE(1);

    f32x4 acc[4][5];
    #pragma unroll
    for (int i = 0; i < 4; ++i)
        #pragma unroll
        for (int j = 0; j < 5; ++j) acc[i][j] = (f32x4)(0.f);
    const int asl = (thi ^ ((tl >> 1) & 3)) * 8;
    const int ar0 = (wr * 64 + tl) * 32;
    const int br0 = (wn * 80 + tl) * 328;

#define ESTEP(KB, VN) { \
    asm volatile("s_waitcnt vmcnt(" #VN ")" ::: "memory"); \
    __builtin_amdgcn_s_barrier(); \
    __builtin_amdgcn_sched_barrier(0); \
    if ((KB) + 2 < 10) ESTAGE((KB) + 2); \
    TCOMP(KB, (&As3[(KB) % 3][0])); }

    ESTEP(0, 2) ESTEP(1, 2) ESTEP(2, 2) ESTEP(3, 2) ESTEP(4, 2)
    ESTEP(5, 2) ESTEP(6, 2) ESTEP(7, 2) ESTEP(8, 2) ESTEP(9, 0)
#undef ESTEP
#undef ESTAGE

    // epilogue: row = m0+wr*64+fr*16+tl ; cols c0..c0+3 = n0+wn*80+fc*16+thi*4
    #pragma unroll
    for (int fr = 0; fr < 4; ++fr) {
        const long row = m0 + wr * 64 + fr * 16 + tl;
        #pragma unroll
        for (int fc = 0; fc < 5; ++fc) {
            const int c0 = n0 + wn * 80 + fc * 16 + thi * 4;
            f32x4 v = acc[fr][fc];
            if (bias && c0 < 300) {
                const float4 bs = *(const float4*)&bias[c0];
                v[0] += bs.x; v[1] += bs.y; v[2] += bs.z; v[3] += bs.w;
            }
            uint2 p;
            p.x = (u32)f2b(v[0]) | ((u32)f2b(v[1]) << 16);
            p.y = (u32)f2b(v[2]) | ((u32)f2b(v[3]) << 16);
            *(uint2*)&outB[row * 320 + c0] = p;
        }
    }
}

// ---------------- h-update egemm with fused mb gather: A = bf16(fhb[src[e]] - hb[e^1]) ----------------
// Same structure; A reg-staged (gather) 2-chunks ahead, ds_write after barrier, 2 LDS A-bufs.
__global__ __launch_bounds__(512, 2) void egemmmb_k(
    const u16* __restrict__ fhb, const u16* __restrict__ hb,
    const int* __restrict__ srcidx, const u16* __restrict__ Bswz,
    const float* __restrict__ bias, const float* __restrict__ xf,
    const u16* __restrict__ xbp, u16* __restrict__ outB)
{
    __shared__ __attribute__((aligned(16))) u16 Bs[160 * 328];
    __shared__ __attribute__((aligned(16))) u16 As2[2][256 * 32];
    const int tid = threadIdx.x;
    const int wf = tid >> 6, lane = tid & 63;
    const int wr = wf & 3, wn = wf >> 2;
    const int tl = lane & 15, thi = lane >> 4;
    const int thi8 = thi * 8;
    const long m0 = (long)(blockIdx.x >> 1) * 256;
    const int n0 = (blockIdx.x & 1) * 160;
    const int wf_u = __builtin_amdgcn_readfirstlane(wf);
    const u16* Bsrc = Bswz + (blockIdx.x & 1) * BH_U16;

    #pragma unroll
    for (int i = 0; i < 13; ++i) {
        int t = i * 512 + tid;
        if (t < 6560)
            GLOAD16(Bsrc + (long)t * 8, &Bs[(i * 512 + wf_u * 64) * 8]);
    }
    const int r_ = tid >> 2;
    const int g_ = (tid & 3) ^ ((r_ >> 1) & 3);
    const long e0 = m0 + r_, e1 = m0 + 128 + r_;
    const int si0 = srcidx[e0], si1 = srcidx[e1];
    const u16* pF0 = fhb + (long)si0 * 320 + g_ * 8;
    const u16* pH0 = hb + (e0 ^ 1) * 320 + g_ * 8;
    const u16* pF1 = fhb + (long)si1 * 320 + g_ * 8;
    const u16* pH1 = hb + (e1 ^ 1) * 320 + g_ * 8;

    uint4 Fa0, Ha0, Fa1, Ha1, Fb0, Hb0, Fb1, Hb1;

#define MLOAD(KB, LF0, LH0, LF1, LH1) { \
    LF0 = *(const uint4*)(pF0 + (KB) * 32); LH0 = *(const uint4*)(pH0 + (KB) * 32); \
    LF1 = *(const uint4*)(pF1 + (KB) * 32); LH1 = *(const uint4*)(pH1 + (KB) * 32); }

#define MWRITE(KB, SF0, SH0, SF1, SH1) { \
    u16* wb_ = &As2[(KB) & 1][0]; \
    uint4 o_; \
    o_.x = bsub2(SF0.x, SH0.x); o_.y = bsub2(SF0.y, SH0.y); \
    o_.z = bsub2(SF0.z, SH0.z); o_.w = bsub2(SF0.w, SH0.w); \
    *(uint4*)&wb_[tid * 8] = o_; \
    o_.x = bsub2(SF1.x, SH1.x); o_.y = bsub2(SF1.y, SH1.y); \
    o_.z = bsub2(SF1.z, SH1.z); o_.w = bsub2(SF1.w, SH1.w); \
    *(uint4*)&wb_[(tid + 512) * 8] = o_; }

    MLOAD(0, Fa0, Ha0, Fa1, Ha1);
    MLOAD(1, Fb0, Hb0, Fb1, Hb1);
    asm volatile("s_waitcnt vmcnt(4)" ::: "memory");
    MWRITE(0, Fa0, Ha0, Fa1, Ha1);

    f32x4 acc[4][5];
    #pragma unroll
    for (int i = 0; i < 4; ++i)
        #pragma unroll
        for (int j = 0; j < 5; ++j) acc[i][j] = (f32x4)(0.f);
    const int asl = (thi ^ ((tl >> 1) & 3)) * 8;
    const int ar0 = (wr * 64 + tl) * 32;
    const int br0 = (wn * 80 + tl) * 328;

#define MSTEP(KB, VN, LF0, LH0, LF1, LH1, SF0, SH0, SF1, SH1) { \
    if ((KB) + 2 < 10) MLOAD((KB) + 2, LF0, LH0, LF1, LH1); \
    asm volatile("s_waitcnt vmcnt(" #VN ")" ::: "memory"); \
    asm volatile("s_waitcnt lgkmcnt(0)" ::: "memory"); \
    __builtin_amdgcn_s_barrier(); \
    __builtin_amdgcn_sched_barrier(0); \
    if ((KB) + 1 < 10) MWRITE((KB) + 1, SF0, SH0, SF1, SH1); \
    TCOMP(KB, (&As2[(KB) & 1][0])); }

    MSTEP(0, 4, Fa0, Ha0, Fa1, Ha1, Fb0, Hb0, Fb1, Hb1)
    MSTEP(1, 4, Fb0, Hb0, Fb1, Hb1, Fa0, Ha0, Fa1, Ha1)
    MSTEP(2, 4, Fa0, Ha0, Fa1, Ha1, Fb0, Hb0, Fb1, Hb1)
    MSTEP(3, 4, Fb0, Hb0, Fb1, Hb1, Fa0, Ha0, Fa1, Ha1)
    MSTEP(4, 4, Fa0, Ha0, Fa1, Ha1, Fb0, Hb0, Fb1, Hb1)
    MSTEP(5, 4, Fb0, Hb0, Fb1, Hb1, Fa0, Ha0, Fa1, Ha1)
    MSTEP(6, 4, Fa0, Ha0, Fa1, Ha1, Fb0, Hb0, Fb1, Hb1)
    MSTEP(7, 4, Fb0, Hb0, Fb1, Hb1, Fa0, Ha0, Fa1, Ha1)
    MSTEP(8, 0, Fa0, Ha0, Fa1, Ha1, Fb0, Hb0, Fb1, Hb1)
    MSTEP(9, 0, Fb0, Hb0, Fb1, Hb1, Fa0, Ha0, Fa1, Ha1)
#undef MSTEP
#undef MLOAD
#undef MWRITE

    // epilogue: h = relu(x + acc + bias)
    #pragma unroll
    for (int fr = 0; fr < 4; ++fr) {
        const long row = m0 + wr * 64 + fr * 16 + tl;
        #pragma unroll
        for (int fc = 0; fc < 5; ++fc) {
            const int c0 = n0 + wn * 80 + fc * 16 + thi * 4;
            f32x4 v = acc[fr][fc];
            if (bias && c0 < 300) {
                const float4 bs = *(const float4*)&bias[c0];
                v[0] += bs.x; v[1] += bs.y; v[2] += bs.z; v[3] += bs.w;
            }
            if (xbp) {
                const ushort4 xb = *(const ushort4*)&xbp[row * 320 + c0];
                v[0] += b2f(xb.x); v[1] += b2f(xb.y); v[2] += b2f(xb.z); v[3] += b2f(xb.w);
            } else if (xf && c0 < 300) {
                const float4 xv = *(const float4*)&xf[row * 300 + c0];
                v[0] += xv.x; v[1] += xv.y; v[2] += xv.z; v[3] += xv.w;
            }
            v[0] = fmaxf(v[0], 0.f); v[1] = fmaxf(v[1], 0.f);
            v[2] = fmaxf(v[2], 0.f); v[3] = fmaxf(v[3], 0.f);
            uint2 p;
            p.x = (u32)f2b(v[0]) | ((u32)f2b(v[1]) << 16);
            p.y = (u32)f2b(v[2]) | ((u32)f2b(v[3]) << 16);
            *(uint2*)&outB[row * 320 + c0] = p;
        }
    }
}

// ---------------- old-style GEMM kept only for KP=960 final projection ----------------
#define LOADB(bq, kt1) { const long ko_ = (long)(kt1) << 6; \
    _Pragma("unroll") for (int fc = 0; fc < 5; ++fc) \
      _Pragma("unroll") for (int ks = 0; ks < 2; ++ks) \
        bq[fc][ks] = *(const bf16x8*)(gBw + (long)fc * 16 * KP + ko_ + ks * 32); }

#define READA(lkt) { \
    _Pragma("unroll") for (int fr = 0; fr < 4; ++fr) \
      _Pragma("unroll") for (int ks = 0; ks < 2; ++ks) \
        a[fr][ks] = *(const bf16x8*)&As[(fr * 16 + tl) * 320 + ((((lkt) * 8 + ks * 4 + thi) ^ sx) * 8)]; }

#define DOMFMA(bq) { _Pragma("unroll") for (int fr = 0; fr < 4; ++fr) \
    _Pragma("unroll") for (int fc = 0; fc < 5; ++fc) \
      _Pragma("unroll") for (int ks = 0; ks < 2; ++ks) \
        acc[fr][fc] = __builtin_amdgcn_mfma_f32_16x16x32_bf16(bq[fc][ks], a[fr][ks], acc[fr][fc], 0, 0, 0); }

template<int KP>
__global__ __launch_bounds__(256, 2) void gemm_k(
    const u16* __restrict__ A,
    const u16* __restrict__ BT,
    const float* __restrict__ bias,
    float* __restrict__ outF, int ostride, int ocols)
{
    __shared__ u16 As[64 * 320];
    const int tid = threadIdx.x;
    const int w = tid >> 6, lane = tid & 63;
    const int tl = lane & 15, thi = lane >> 4;
    const int sx = tl & 7;
    const long m0 = (long)blockIdx.x * 64;
    const int w_u = __builtin_amdgcn_readfirstlane(w);

    const u16* gBw = BT + ((long)(w * 80 + tl)) * KP + thi * 8;

    f32x4 acc[4][5];
    #pragma unroll
    for (int i = 0; i < 4; ++i)
        #pragma unroll
        for (int j = 0; j < 5; ++j) acc[i][j] = (f32x4)(0.f);

    constexpr int NCH = KP / 320;
    constexpr int NST = KP >> 6;
    bf16x8 bA[5][2], bB[5][2], a[4][2];

    #pragma unroll
    for (int kb = 0; kb < NCH; ++kb) {
        if (kb) __syncthreads();
        #pragma unroll
        for (int i = 0; i < 10; ++i) {
            const int c = i * 256 + w_u * 64 + lane;
            const int r = c / 40, s = c - r * 40;
            GLOAD16(A + (m0 + r) * (long)KP + kb * 320 + ((s ^ (r & 7)) * 8),
                    &As[(i * 256 + w_u * 64) * 8]);
        }
        if (kb == 0) LOADB(bA, 0);
        __syncthreads();
        #pragma unroll
        for (int lkt = 0; lkt < 5; ++lkt) {
            const int kt = kb * 5 + lkt;
            if (kt + 1 < NST) {
                if (kt & 1) { LOADB(bA, kt + 1); } else { LOADB(bB, kt + 1); }
            }
            READA(lkt);
            if (kt & 1) { DOMFMA(bB); } else { DOMFMA(bA); }
        }
    }

    #pragma unroll
    for (int fr = 0; fr < 4; ++fr) {
        const long row = m0 + fr * 16 + tl;
        #pragma unroll
        for (int fc = 0; fc < 5; ++fc) {
            const int c0 = w * 80 + fc * 16 + thi * 4;
            f32x4 v = acc[fr][fc];
            if (bias && c0 < 300) {
                const float4 bs = *(const float4*)&bias[c0];
                v[0] += bs.x; v[1] += bs.y; v[2] += bs.z; v[3] += bs.w;
            }
            if (c0 < ocols)
                *(float4*)&outF[row * (long)ostride + c0] = make_float4(v[0], v[1], v[2], v[3]);
        }
    }
}

// ---------------- fused 8-key 4-head attention, one wave per node (bf16 Q/FV) ----------------
__global__ __launch_bounds__(256) void attn_k(
    const u16* __restrict__ Q, const u16* __restrict__ FV,
    const u16* __restrict__ HK, const u16* __restrict__ HV,
    const int* __restrict__ mail, u16* __restrict__ Ob)
{
    const int tid = threadIdx.x;
    const long n = (long)blockIdx.x * 4 + (tid >> 6);
    const int lane = tid & 63, g = lane >> 4, t = lane & 15;
    const float scale = 0.115470054f;  // 1/sqrt(75)
    const int dbase = g * 75 + t;

    float q[5];
    #pragma unroll
    for (int r = 0; r < 5; ++r)
        q[r] = (t + 16 * r < 75) ? b2f(Q[n * 320 + dbase + 16 * r]) * scale : 0.f;

    int idx[8]; float s[8];
    #pragma unroll
    for (int j = 0; j < 8; ++j) {
        idx[j] = mail[n * 8 + j];
        const u16* kr = HK + (long)idx[j] * 320 + dbase;
        float p = 0.f;
        #pragma unroll
        for (int r = 0; r < 5; ++r) p += q[r] * b2f(kr[16 * r]);
        p += __shfl_xor(p, 8, 64);
        p += __shfl_xor(p, 4, 64);
        p += __shfl_xor(p, 2, 64);
        p += __shfl_xor(p, 1, 64);
        s[j] = p;
    }
    float mx = s[0];
    #pragma unroll
    for (int j = 1; j < 8; ++j) mx = fmaxf(mx, s[j]);
    float sum = 0.f;
    #pragma unroll
    for (int j = 0; j < 8; ++j) { s[j] = __expf(s[j] - mx); sum += s[j]; }
    const float inv = 1.f / sum;

    float o[5];
    #pragma unroll
    for (int r = 0; r < 5; ++r) o[r] = b2f(FV[n * 320 + dbase + 16 * r]);  // softmax sums to 1
    #pragma unroll
    for (int j = 0; j < 8; ++j) {
        const float pj = s[j] * inv;
        const u16* vr = HV + (long)idx[j] * 320 + dbase;
        #pragma unroll
        for (int r = 0; r < 5; ++r) o[r] += pj * b2f(vr[16 * r]);
    }
    #pragma unroll
    for (int r = 0; r < 5; ++r)
        if (t + 16 * r < 75) Ob[n * 320 + dbase + 16 * r] = f2b(o[r]);
    if (lane < 20) Ob[n * 320 + 300 + lane] = 0;   // zero pad cols
}

// ---------------- build concat A = [mail_sum | f_h | f] (bf16, N x 960) ----------------
__global__ __launch_bounds__(256) void concat_k(
    const u16* __restrict__ hb, const u16* __restrict__ fhb,
    const float* __restrict__ f, const int* __restrict__ mail,
    u16* __restrict__ Acat)
{
    const long n = blockIdx.x;
    int m[8];
    #pragma unroll
    for (int j = 0; j < 8; ++j) m[j] = mail[n * 8 + j];
    for (int c = threadIdx.x; c < 960; c += 256) {
        float v;
        if (c < 300) {
            float s = 0.f;
            #pragma unroll
            for (int j = 0; j < 8; ++j) s += b2f(hb[(long)m[j] * 320 + c]);
            v = s;
        } else if (c < 600) v = b2f(fhb[n * 320 + (c - 300)]);
        else if (c < 900) v = f[n * 300 + (c - 600)];
        else v = 0.f;
        Acat[n * 960 + c] = f2b(v);
    }
}

extern "C" void kernel_launch(void* const* d_in, const int* in_sizes, int n_in,
                              void* d_out, int out_size, void* d_ws, size_t ws_size,
                              hipStream_t stream)
{
    const int N = N_NODES, E = E_EDGES;
    const float* f    = (const float*)d_in[0];
    const float* x    = (const float*)d_in[1];
    const int*   mail = (const int*)d_in[2];
    const int*   srcx = (const int*)d_in[3];
    const float* Wq = (const float*)d_in[4];   const float* bq = (const float*)d_in[5];
    const float* Wk = (const float*)d_in[6];   const float* bk = (const float*)d_in[7];
    const float* Wv = (const float*)d_in[8];   const float* bv = (const float*)d_in[9];
    const float* Wo = (const float*)d_in[10];  const float* bo = (const float*)d_in[11];
    const float* Wmp = (const float*)d_in[12]; const float* bmp = (const float*)d_in[13];
    const float* Wlast = (const float*)d_in[14]; const float* blast = (const float*)d_in[15];
    float* out = (float*)d_out;

    char* ws = (char*)d_ws;
    size_t off = 0;
    auto alloc = [&](size_t b) -> void* {
        void* p = ws + off; off += (b + 255) & ~(size_t)255; return p;
    };
    u16* hb   = (u16*)alloc((size_t)E * DP * 2);   // h (bf16, padded)
    u16* HKb  = (u16*)alloc((size_t)E * DP * 2);   // HK
    u16* HVb  = (u16*)alloc((size_t)E * DP * 2);   // HV; reused as Acat
    u16* Qb   = (u16*)alloc((size_t)N * DP * 2);
    u16* FVb  = (u16*)alloc((size_t)N * DP * 2);
    u16* fhb  = (u16*)alloc((size_t)N * DP * 2);
    u16* Ob   = (u16*)alloc((size_t)N * DP * 2);
    u16* WqS  = (u16*)alloc((size_t)2 * BH_U16 * 2);
    u16* WkS  = (u16*)alloc((size_t)2 * BH_U16 * 2);
    u16* WvS  = (u16*)alloc((size_t)2 * BH_U16 * 2);
    u16* WoS  = (u16*)alloc((size_t)2 * BH_U16 * 2);
    u16* Wm0S = (u16*)alloc((size_t)2 * BH_U16 * 2);
    u16* Wm1S = (u16*)alloc((size_t)2 * BH_U16 * 2);
    u16* WcatB = (u16*)alloc((size_t)KCAT * 320 * 2);
    u16* xb = nullptr;
    if (ws_size >= off + (size_t)E * DP * 2) xb = (u16*)alloc((size_t)E * DP * 2);

    // ---- weights ----
    {
        int blks = (2 * 160 * 328 + 255) / 256;
        convTswz_k<<<blks, 256, 0, stream>>>(Wq, WqS);
        convTswz_k<<<blks, 256, 0, stream>>>(Wk, WkS);
        convTswz_k<<<blks, 256, 0, stream>>>(Wv, WvS);
        convTswz_k<<<blks, 256, 0, stream>>>(Wo, WoS);
        convTswz_k<<<blks, 256, 0, stream>>>(Wmp, Wm0S);
        convTswz_k<<<blks, 256, 0, stream>>>(Wmp + 90000, Wm1S);
        long totc = (long)320 * KCAT;
        convT_k<<<(int)((totc + 255) / 256), 256, 0, stream>>>(Wlast, 900, 300, WcatB, KCAT, totc);
    }
    // ---- activations: h0 = bf16(x) (+xb copy), fh0 = bf16(f) ----
    {
        long totE = (long)E * (DP / 8);
        padconv_k<<<(int)((totE + 255) / 256), 256, 0, stream>>>(x, 300, hb, xb, DP, totE);
        long totN = (long)N * (DP / 8);
        padconv_k<<<(int)((totN + 255) / 256), 256, 0, stream>>>(f, 300, fhb, nullptr, DP, totN);
    }

    const int GN = (N / 256) * 2;   // 256
    const int GE = (E / 256) * 2;   // 2048

    for (int it = 0; it < 2; ++it) {
        const u16* WmS = it ? Wm1S : Wm0S;
        const float* bmpi = bmp + it * 300;
        // Q = f_h @ Wq + bq ; FV = f_h @ Wv + bv   (bf16)
        egemm_k<<<GN, 512, 0, stream>>>(fhb, WqS, bq, Qb);
        egemm_k<<<GN, 512, 0, stream>>>(fhb, WvS, bv, FVb);
        // HK = h @ Wk + bk ; HV = h @ Wv            (bf16)
        egemm_k<<<GE, 512, 0, stream>>>(hb, WkS, bk, HKb);
        egemm_k<<<GE, 512, 0, stream>>>(hb, WvS, nullptr, HVb);
        // attention -> Ob (bf16)
        attn_k<<<N / 4, 256, 0, stream>>>(Qb, FVb, HKb, HVb, mail, Ob);
        // f_h = O @ Wo + bo (bf16)
        egemm_k<<<GN, 512, 0, stream>>>(Ob, WoS, bo, fhb);
        // h = relu(x + (fhb[src]-hb[e^1]) @ Wmp + bmp)
        const float* a2f = (xb || it == 0) ? nullptr : x;
        const u16*   a2b = xb ? xb : (it == 0 ? hb : nullptr);
        egemmmb_k<<<GE, 512, 0, stream>>>(fhb, hb, srcx, WmS, bmpi, a2f, a2b, hb);
    }

    // Acat = [mail_sum | f_h | f]  (reuse HVb)
    concat_k<<<N, 256, 0, stream>>>(hb, fhb, f, mail, HVb);
    // out = Acat @ Wlast + blast   (f32, stride 300)
    gemm_k<960><<<N / 64, 256, 0, stream>>>(HVb, WcatB, blast, out, 300, 300);
}